// Round 7
// baseline (1272.409 us; speedup 1.0000x reference)
//
#include <hip/hip_runtime.h>

#define USERN 50000
#define ITEMN 20000
#define NN    70000
#define DTOT  256        // 4 branches x 64
#define LAMv  0.2f
#define E_MAINN  2000000
#define E_MODALN 1000000
#define SCAN_NBLK 35     // ceil(NN / 2048)
#define R0BITS 4
#define NBUCK  (NN >> R0BITS)   // 4375 buckets of 16 rows (70000 = 4375*16)

typedef float  v4f  __attribute__((ext_vector_type(4)));
typedef float  v8f  __attribute__((ext_vector_type(8)));
typedef short  v8s  __attribute__((ext_vector_type(8)));
typedef unsigned short v8u __attribute__((ext_vector_type(8)));

// ---------- bf16 helpers ----------
__device__ inline unsigned short f2bf(float f) {           // RNE
    unsigned u = __float_as_uint(f);
    u += 0x7FFFu + ((u >> 16) & 1u);
    return (unsigned short)(u >> 16);
}
__device__ inline v8f bf8f(v8u u) {
    v8f f;
    #pragma unroll
    for (int i = 0; i < 8; ++i) f[i] = __uint_as_float((unsigned)u[i] << 16);
    return f;
}
__device__ inline v8u f8bf(v8f f) {
    v8u u;
    #pragma unroll
    for (int i = 0; i < 8; ++i) u[i] = f2bf(f[i]);
    return u;
}
__device__ inline ushort4 f4bf(float4 f) {
    return make_ushort4(f2bf(f.x), f2bf(f.y), f2bf(f.z), f2bf(f.w));
}

// ---------------- W transpose+cvt: Wtb[c][k], c<64 from W0 else W1 -------------------------
__global__ __launch_bounds__(256) void wt_build(
    const float* __restrict__ W0, const float* __restrict__ W1, int K,
    unsigned short* __restrict__ Wtb)
{
    int idx = blockIdx.x * 256 + threadIdx.x;
    if (idx >= 128 * K) return;
    int c = idx / K, k = idx - c * K;
    float v = (c < 64) ? W0[(size_t)k * 64 + c] : W1[(size_t)k * 64 + (c - 64)];
    Wtb[idx] = f2bf(v);
}

// ---------------- MFMA GEMM: P[seg][M][256] partials, K-split x2 ---------------------------
#define LDK 40   // padded k-stride in LDS (80B rows -> conflict-free b128)

__global__ __launch_bounds__(256) void gemm_mfma(
    const float* __restrict__ A, int M, int K,
    const unsigned short* __restrict__ Wtb,
    float* __restrict__ P, int blkA, int blkB)
{
    __shared__ __align__(16) unsigned short As[64 * LDK];
    __shared__ __align__(16) unsigned short Ws[128 * LDK];
    const int tid  = threadIdx.x;
    const int row0 = blockIdx.x * 64;
    const int segLen = K >> 1;
    const int k0   = blockIdx.y * segLen;
    const int kend = k0 + segLen;
    float* outP = P + (size_t)blockIdx.y * ITEMN * DTOT;

    const int w   = tid >> 6;
    const int l   = tid & 63;
    const int l16 = l & 15, kg = l >> 4;

    const int sar = tid >> 2, sak = (tid & 3) * 8;
    const int swc = tid >> 1, swk = (tid & 1) * 16;

    v4f acc[8];
    #pragma unroll
    for (int n = 0; n < 8; ++n) acc[n] = (v4f)0.f;

    for (int kt = k0; kt < kend; kt += 32) {
        __syncthreads();
        {
            int arow = row0 + sar; if (arow >= M) arow = M - 1;
            const float* ap = A + (size_t)arow * K + kt + sak;
            float4 a0 = ((const float4*)ap)[0];
            float4 a1 = ((const float4*)ap)[1];
            *(ushort4*)&As[sar * LDK + sak]     = f4bf(a0);
            *(ushort4*)&As[sar * LDK + sak + 4] = f4bf(a1);
            const unsigned short* wp = Wtb + (size_t)swc * K + kt + swk;
            *(uint4*)&Ws[swc * LDK + swk]     = ((const uint4*)wp)[0];
            *(uint4*)&Ws[swc * LDK + swk + 8] = ((const uint4*)wp)[1];
        }
        __syncthreads();

        v8s af = *(const v8s*)&As[(w * 16 + l16) * LDK + kg * 8];
        #pragma unroll
        for (int n = 0; n < 8; ++n) {
            v8s bf = *(const v8s*)&Ws[(n * 16 + l16) * LDK + kg * 8];
            acc[n] = __builtin_amdgcn_mfma_f32_16x16x32_bf16(af, bf, acc[n], 0, 0, 0);
        }
    }

    #pragma unroll
    for (int n = 0; n < 8; ++n) {
        const int col  = n * 16 + l16;
        const int gcol = (col < 64) ? blkA * 64 + col : blkB * 64 + (col - 64);
        #pragma unroll
        for (int r = 0; r < 4; ++r) {
            int row = row0 + w * 16 + kg * 4 + r;
            if (row < M) outP[(size_t)row * DTOT + gcol] = acc[n][r];
        }
    }
}

// ------- build feats: X1b user=uE, item=l2norm(P-reduce+bias); X2b item=iE ----------------
__global__ __launch_bounds__(256) void build_feats(
    const float* __restrict__ P,
    const float* __restrict__ u_sh, const float* __restrict__ u_vsp, const float* __restrict__ u_tsp,
    const float* __restrict__ i_sh, const float* __restrict__ i_vsp, const float* __restrict__ i_tsp,
    const float* __restrict__ bi_sh, const float* __restrict__ bt_sh,
    const float* __restrict__ bi_vsp, const float* __restrict__ bt_tsp,
    unsigned short* __restrict__ X1b, unsigned short* __restrict__ X2b)
{
    const int n = blockIdx.x;
    const int t = threadIdx.x;
    const int b = t >> 6, k = t & 63;
    if (n < USERN) {
        const float* u = (b < 2) ? u_sh : (b == 2 ? u_vsp : u_tsp);
        X1b[(size_t)n * DTOT + t] = f2bf(u[(size_t)n * 64 + k]);
    } else {
        const int it = n - USERN;
        const size_t SEG = (size_t)ITEMN * DTOT;
        size_t idx = (size_t)it * DTOT + t;
        float f = P[idx] + P[idx + SEG];
        const float* bias = (b == 0) ? bi_sh : (b == 1 ? bt_sh : (b == 2 ? bi_vsp : bt_tsp));
        f += bias[k];
        float s = f * f;
        #pragma unroll
        for (int off = 32; off > 0; off >>= 1) s += __shfl_xor(s, off, 64);
        X1b[(size_t)n * DTOT + t] = f2bf(f / fmaxf(sqrtf(s), 1e-12f));
        const float* p = (b < 2) ? i_sh : (b == 2 ? i_vsp : i_tsp);
        X2b[(size_t)n * DTOT + t] = f2bf(p[(size_t)it * 64 + k]);
    }
}

// ---------------- CSR build: histogram, 2-kernel scan, bucketed 2-phase scatter ------------
__global__ __launch_bounds__(256) void hist3(
    const int* __restrict__ ar, const int* __restrict__ mir, const int* __restrict__ mtr,
    int* __restrict__ cntA, int* __restrict__ cntI, int* __restrict__ cntT)
{
    const int total = E_MAINN + 2 * E_MODALN;
    for (int i = blockIdx.x * blockDim.x + threadIdx.x; i < total; i += gridDim.x * blockDim.x) {
        if (i < E_MAINN)                    atomicAdd(&cntA[ar[i]], 1);
        else if (i < E_MAINN + E_MODALN)    atomicAdd(&cntI[mir[i - E_MAINN]], 1);
        else                                atomicAdd(&cntT[mtr[i - E_MAINN - E_MODALN]], 1);
    }
}

__device__ inline int wave_incl_scan64(int x, int lane) {
    #pragma unroll
    for (int off = 1; off < 64; off <<= 1) {
        int t = __shfl_up(x, off, 64);
        if (lane >= off) x += t;
    }
    return x;
}

__global__ __launch_bounds__(1024) void scan_bsum(
    const int* __restrict__ cntA, const int* __restrict__ cntI, const int* __restrict__ cntT,
    int* __restrict__ partial)
{
    const int g = blockIdx.y;
    const int* cnt = (g == 0) ? cntA : (g == 1 ? cntI : cntT);
    int i0 = blockIdx.x * 2048 + threadIdx.x;
    int i1 = i0 + 1024;
    int v = ((i0 < NN) ? cnt[i0] : 0) + ((i1 < NN) ? cnt[i1] : 0);
    __shared__ int ws[16];
    const int lane = threadIdx.x & 63, wv = threadIdx.x >> 6;
    #pragma unroll
    for (int off = 32; off > 0; off >>= 1) v += __shfl_xor(v, off, 64);
    if (lane == 0) ws[wv] = v;
    __syncthreads();
    if (threadIdx.x == 0) {
        int s = 0;
        #pragma unroll
        for (int i = 0; i < 16; ++i) s += ws[i];
        partial[g * SCAN_NBLK + blockIdx.x] = s;
    }
}

__global__ __launch_bounds__(1024) void scan_write(
    const int* __restrict__ cntA, const int* __restrict__ cntI, const int* __restrict__ cntT,
    const int* __restrict__ partial,
    int* __restrict__ rpA, int* __restrict__ rpI, int* __restrict__ rpT)
{
    const int g = blockIdx.y;
    const int* cnt = (g == 0) ? cntA : (g == 1 ? cntI : cntT);
    int* rp        = (g == 0) ? rpA  : (g == 1 ? rpI  : rpT);
    __shared__ int sbase;
    __shared__ int wsum[16];
    const int tid = threadIdx.x, lane = tid & 63, wv = tid >> 6;
    if (tid == 0) {
        int s = 0;
        for (int i = 0; i < (int)blockIdx.x; ++i) s += partial[g * SCAN_NBLK + i];
        sbase = s;
    }
    __syncthreads();
    int run = sbase;
    const int base = blockIdx.x * 2048;
    #pragma unroll
    for (int c = 0; c < 2; ++c) {
        int i = base + c * 1024 + tid;
        int v = (i < NN) ? cnt[i] : 0;
        int x = wave_incl_scan64(v, lane);
        if (lane == 63) wsum[wv] = x;
        __syncthreads();
        if (wv == 0 && lane < 16) {
            int s = wsum[lane];
            #pragma unroll
            for (int off = 1; off < 16; off <<= 1) {
                int t = __shfl_up(s, off, 64);
                if (lane >= off) s += t;
            }
            wsum[lane] = s;
        }
        __syncthreads();
        int woff = (wv > 0) ? wsum[wv - 1] : 0;
        if (i < NN)       rp[i]  = run + woff + x - v;
        else if (i == NN) rp[NN] = run + woff + x;
        run += wsum[15];
        __syncthreads();
    }
}

// Phase A: append edges into bucket-contiguous tmp regions (line-merged writes).
// tmp entry: x = row_local(4b)<<17 | col(17b), y = f32 val bits.
__global__ __launch_bounds__(256) void partition3(
    const int* __restrict__ ar,  const int* __restrict__ ac,  const float* __restrict__ av,
    const int* __restrict__ mir, const int* __restrict__ mic, const float* __restrict__ miv,
    const int* __restrict__ mtr, const int* __restrict__ mtc, const float* __restrict__ mtv,
    const int* __restrict__ rpA, const int* __restrict__ rpI, const int* __restrict__ rpT,
    int* __restrict__ bcnt,
    uint2* __restrict__ tmpA, uint2* __restrict__ tmpI, uint2* __restrict__ tmpT)
{
    const int total = E_MAINN + 2 * E_MODALN;
    for (int i = blockIdx.x * blockDim.x + threadIdx.x; i < total; i += gridDim.x * blockDim.x) {
        if (i < E_MAINN) {
            int r = ar[i], b = r >> R0BITS;
            int pos = rpA[b << R0BITS] + atomicAdd(&bcnt[b], 1);
            tmpA[pos] = make_uint2(((unsigned)(r & 15) << 17) | (unsigned)ac[i], __float_as_uint(av[i]));
        } else if (i < E_MAINN + E_MODALN) {
            int e = i - E_MAINN;
            int r = mir[e], b = r >> R0BITS;
            int pos = rpI[b << R0BITS] + atomicAdd(&bcnt[NBUCK + b], 1);
            tmpI[pos] = make_uint2(((unsigned)(r & 15) << 17) | (unsigned)mic[e], __float_as_uint(miv[e]));
        } else {
            int e = i - E_MAINN - E_MODALN;
            int r = mtr[e], b = r >> R0BITS;
            int pos = rpT[b << R0BITS] + atomicAdd(&bcnt[2 * NBUCK + b], 1);
            tmpT[pos] = make_uint2(((unsigned)(r & 15) << 17) | (unsigned)mtc[e], __float_as_uint(mtv[e]));
        }
    }
}

// Phase B: per-bucket local scatter into final CSR order (writes stay in a ~few-KB window).
__global__ __launch_bounds__(256) void local_scatter(
    const int* __restrict__ rpA, const int* __restrict__ rpI, const int* __restrict__ rpT,
    const uint2* __restrict__ tmpA, const uint2* __restrict__ tmpI, const uint2* __restrict__ tmpT,
    uint2* __restrict__ evA, uint2* __restrict__ evI, uint2* __restrict__ evT)
{
    const int g = blockIdx.y;
    const int* rp     = (g == 0) ? rpA  : (g == 1 ? rpI  : rpT);
    const uint2* tmp  = (g == 0) ? tmpA : (g == 1 ? tmpI : tmpT);
    uint2* ev         = (g == 0) ? evA  : (g == 1 ? evI  : evT);
    const int r0 = blockIdx.x << R0BITS;
    __shared__ int lrp[17];
    __shared__ int lcnt[16];
    const int tid = threadIdx.x;
    if (tid < 17) lrp[tid] = rp[r0 + tid];
    if (tid < 16) lcnt[tid] = 0;
    __syncthreads();
    const int base = lrp[0];
    const int count = lrp[16] - base;
    for (int t = tid; t < count; t += 256) {
        uint2 q = tmp[base + t];
        int rl = q.x >> 17;
        int k = atomicAdd(&lcnt[rl], 1);
        ev[lrp[rl] + k] = make_uint2(q.x & 0x1FFFFu, q.y);
    }
}

// -------- CSR SpMM: wave/row, half-wave per edge, 16B lanes, 8 edges in flight -------------
#define SPMM8_HEAD                                                                  \
    const int w = (blockIdx.x * blockDim.x + threadIdx.x) >> 6;                     \
    if (w >= NN) return;                                                            \
    const int lane = threadIdx.x & 63;                                              \
    const int half = lane >> 5, l5 = lane & 31;                                     \
    const v8u* __restrict__ Xv = (const v8u*)Xb;                                    \
    int e = rp[w]; const int end = rp[w + 1];                                       \
    v8f acc = (v8f)0.f;                                                             \
    for (; e + 8 <= end; e += 8) {                                                  \
        uint2 q0 = ev[e + half],     q1 = ev[e + 2 + half];                         \
        uint2 q2 = ev[e + 4 + half], q3 = ev[e + 6 + half];                         \
        v8f g0 = bf8f(Xv[(size_t)q0.x * 32 + l5]);                                  \
        v8f g1 = bf8f(Xv[(size_t)q1.x * 32 + l5]);                                  \
        v8f g2 = bf8f(Xv[(size_t)q2.x * 32 + l5]);                                  \
        v8f g3 = bf8f(Xv[(size_t)q3.x * 32 + l5]);                                  \
        float v0 = __uint_as_float(q0.y), v1 = __uint_as_float(q1.y);               \
        float v2 = __uint_as_float(q2.y), v3 = __uint_as_float(q3.y);               \
        _Pragma("unroll")                                                           \
        for (int i = 0; i < 8; ++i) {                                               \
            acc[i] = fmaf(v0, g0[i], acc[i]); acc[i] = fmaf(v1, g1[i], acc[i]);     \
            acc[i] = fmaf(v2, g2[i], acc[i]); acc[i] = fmaf(v3, g3[i], acc[i]);     \
        }                                                                           \
    }                                                                               \
    for (; e + 2 <= end; e += 2) {                                                  \
        uint2 q = ev[e + half];                                                     \
        v8f g = bf8f(Xv[(size_t)q.x * 32 + l5]);                                    \
        float v = __uint_as_float(q.y);                                             \
        _Pragma("unroll")                                                           \
        for (int i = 0; i < 8; ++i) acc[i] = fmaf(v, g[i], acc[i]);                 \
    }                                                                               \
    if (e < end && half == 0) {                                                     \
        uint2 q = ev[e];                                                            \
        v8f g = bf8f(Xv[(size_t)q.x * 32 + l5]);                                    \
        float v = __uint_as_float(q.y);                                             \
        _Pragma("unroll")                                                           \
        for (int i = 0; i < 8; ++i) acc[i] = fmaf(v, g[i], acc[i]);                 \
    }                                                                               \
    _Pragma("unroll")                                                               \
    for (int i = 0; i < 8; ++i) acc[i] += __shfl_xor(acc[i], 32, 64);               \
    if (half != 0) return;                                                          \
    const size_t oidx = (size_t)w * DTOT + l5 * 8;

// E1b = bf16(adj @ X1b); X2b user rows = same
__global__ __launch_bounds__(256) void spmm_e1(
    const int* __restrict__ rp, const uint2* __restrict__ ev,
    const unsigned short* __restrict__ Xb, unsigned short* __restrict__ E1b,
    unsigned short* __restrict__ X2b)
{
    SPMM8_HEAD
    v8u ub = f8bf(acc);
    *(v8u*)&E1b[oidx] = ub;
    if (w < USERN) *(v8u*)&X2b[oidx] = ub;
}

// out = E1b + adj @ X2b   (f32 out)
__global__ __launch_bounds__(256) void fused_comb_main(
    const int* __restrict__ rp, const uint2* __restrict__ ev,
    const unsigned short* __restrict__ Xb, const unsigned short* __restrict__ E1b,
    float* __restrict__ out)
{
    SPMM8_HEAD
    v8f o = bf8f(*(const v8u*)&E1b[oidx]);
    #pragma unroll
    for (int i = 0; i < 8; ++i) o[i] += acc[i];
    *(v8f*)&out[oidx] = o;
}

// C1b = bf16(adj @ OUTb)
__global__ __launch_bounds__(256) void spmm_l1(
    const int* __restrict__ rp, const uint2* __restrict__ ev,
    const unsigned short* __restrict__ Xb, unsigned short* __restrict__ C1b)
{
    SPMM8_HEAD
    *(v8u*)&C1b[oidx] = f8bf(acc);
}

// out += C1b + adj @ C1b   (Xb == C1b)
__global__ __launch_bounds__(256) void fused_final(
    const int* __restrict__ rp, const uint2* __restrict__ ev,
    const unsigned short* __restrict__ Xb, float* __restrict__ out)
{
    SPMM8_HEAD
    v8f o = *(const v8f*)&out[oidx];
    v8f c = bf8f(Xv[(size_t)w * 32 + l5]);
    #pragma unroll
    for (int i = 0; i < 8; ++i) o[i] += c[i] + acc[i];
    *(v8f*)&out[oidx] = o;
}

// -------- modal: wave per (row, modality), quarter-wave per edge, 16B lanes ----------------
__global__ __launch_bounds__(256) void modal_add(
    const int* __restrict__ rpI, const uint2* __restrict__ evI,
    const int* __restrict__ rpT, const uint2* __restrict__ evT,
    const unsigned short* __restrict__ X1b, const unsigned short* __restrict__ X2b,
    float* __restrict__ out, unsigned short* __restrict__ OUTb)
{
    const int gw = (blockIdx.x * blockDim.x + threadIdx.x) >> 6;
    if (gw >= 2 * NN) return;
    const int r = gw >> 1, m = gw & 1;
    const int lane = threadIdx.x & 63;
    const int qt = lane >> 4, l4 = lane & 15;
    const int* rp   = m ? rpT : rpI;
    const uint2* ev = m ? evT : evI;
    const int slot = m * 8 + (l4 >> 3) * 16 + (l4 & 7);     // ushort8 slot (blocks m, m+2)
    const v8u* X1v = (const v8u*)X1b;
    const v8u* X2v = (const v8u*)X2b;
    v8f acc = (v8f)0.f;
    int e = rp[r]; const int end = rp[r + 1];
    for (; e + 4 <= end; e += 4) {
        uint2 q = ev[e + qt];
        const v8u* B = ((int)q.x < USERN) ? X1v : X2v;
        v8f g = bf8f(B[(size_t)q.x * 32 + slot]);
        float v = __uint_as_float(q.y) * LAMv;
        #pragma unroll
        for (int i = 0; i < 8; ++i) acc[i] = fmaf(v, g[i], acc[i]);
    }
    if (qt < end - e) {
        uint2 q = ev[e + qt];
        const v8u* B = ((int)q.x < USERN) ? X1v : X2v;
        v8f g = bf8f(B[(size_t)q.x * 32 + slot]);
        float v = __uint_as_float(q.y) * LAMv;
        #pragma unroll
        for (int i = 0; i < 8; ++i) acc[i] = fmaf(v, g[i], acc[i]);
    }
    #pragma unroll
    for (int i = 0; i < 8; ++i) {
        acc[i] += __shfl_xor(acc[i], 16, 64);
        acc[i] += __shfl_xor(acc[i], 32, 64);
    }
    if (lane < 16) {
        const size_t idx = (size_t)r * DTOT + slot * 8;
        v8f o = *(const v8f*)&out[idx];
        #pragma unroll
        for (int i = 0; i < 8; ++i) o[i] += acc[i];
        *(v8f*)&out[idx] = o;
        *(v8u*)&OUTb[idx] = f8bf(o);
    }
}

extern "C" void kernel_launch(void* const* d_in, const int* in_sizes, int n_in,
                              void* d_out, int out_size, void* d_ws, size_t ws_size,
                              hipStream_t stream)
{
    const float* img = (const float*)d_in[0];
    const float* txt = (const float*)d_in[1];
    const int*   ar  = (const int*)d_in[2];
    const int*   ac  = (const int*)d_in[3];
    const float* av  = (const float*)d_in[4];
    const int*   mir = (const int*)d_in[5];
    const int*   mic = (const int*)d_in[6];
    const float* miv = (const float*)d_in[7];
    const int*   mtr = (const int*)d_in[8];
    const int*   mtc = (const int*)d_in[9];
    const float* mtv = (const float*)d_in[10];
    const float* u_sh   = (const float*)d_in[11];
    const float* i_sh   = (const float*)d_in[12];
    const float* Wi_sh  = (const float*)d_in[13];
    const float* bi_sh  = (const float*)d_in[14];
    const float* Wt_sh  = (const float*)d_in[15];
    const float* bt_sh  = (const float*)d_in[16];
    const float* u_vsp  = (const float*)d_in[17];
    const float* i_vsp  = (const float*)d_in[18];
    const float* Wi_vsp = (const float*)d_in[19];
    const float* bi_vsp = (const float*)d_in[20];
    const float* u_tsp  = (const float*)d_in[21];
    const float* i_tsp  = (const float*)d_in[22];
    const float* Wt_tsp = (const float*)d_in[23];
    const float* bt_tsp = (const float*)d_in[24];

    // -------- workspace layout --------
    const size_t NE = (size_t)NN * DTOT;
    unsigned short* X1b  = (unsigned short*)d_ws;        // 35.84 MB
    unsigned short* X2b  = X1b + NE;                     // 35.84 MB
    unsigned short* OUTb = X2b + NE;                     // 35.84 MB
    unsigned short* E1b  = OUTb + NE;                    // 35.84 MB
    unsigned short* C1b  = X1b;                          // alias: X1b dead after modal_add
    float* P = (float*)(E1b + NE);                       // [2][ITEM,256] f32 = 40.96 MB
    unsigned short* WtbI = (unsigned short*)(P + 2 * (size_t)ITEMN * DTOT);  // 1 MB
    unsigned short* WtbT = WtbI + 128 * 4096;
    uint2* evA  = (uint2*)(WtbT + 128 * 768);            // 16 MB
    uint2* evI  = evA + E_MAINN;                         // 8 MB
    uint2* evT  = evI + E_MODALN;                        // 8 MB
    uint2* tmpA = evT + E_MODALN;                        // 16 MB
    uint2* tmpI = tmpA + E_MAINN;                        // 8 MB
    uint2* tmpT = tmpI + E_MODALN;                       // 8 MB
    int*   rpA   = (int*)(tmpT + E_MODALN);
    int*   rpI   = rpA + (NN + 4);
    int*   rpT   = rpI + (NN + 4);
    int*   cntA  = rpT + (NN + 4);
    int*   cntI  = cntA + NN;
    int*   cntT  = cntI + NN;
    int*   bcnt  = cntT + NN;                            // 3*NBUCK
    int*   partial = bcnt + 3 * NBUCK;                   // 3*SCAN_NBLK+1
    float* out   = (float*)d_out;

    const int waveBlocks  = (NN * 64) / 256;             // 17500
    const int modalBlocks = (2 * NN * 64) / 256;         // 35000

    // -------- CSR build (bucketed two-phase scatter) --------
    hipMemsetAsync(cntA, 0, (3 * (size_t)NN + 3 * NBUCK) * sizeof(int), stream);
    hist3<<<2048, 256, 0, stream>>>(ar, mir, mtr, cntA, cntI, cntT);
    scan_bsum<<<dim3(SCAN_NBLK, 3), 1024, 0, stream>>>(cntA, cntI, cntT, partial);
    scan_write<<<dim3(SCAN_NBLK, 3), 1024, 0, stream>>>(cntA, cntI, cntT, partial, rpA, rpI, rpT);
    partition3<<<2048, 256, 0, stream>>>(ar, ac, av, mir, mic, miv, mtr, mtc, mtv,
                                         rpA, rpI, rpT, bcnt, tmpA, tmpI, tmpT);
    local_scatter<<<dim3(NBUCK, 3), 256, 0, stream>>>(rpA, rpI, rpT, tmpA, tmpI, tmpT, evA, evI, evT);

    // -------- W transpose to bf16 --------
    wt_build<<<(128 * 4096 + 255) / 256, 256, 0, stream>>>(Wi_sh, Wi_vsp, 4096, WtbI);
    wt_build<<<(128 * 768  + 255) / 256, 256, 0, stream>>>(Wt_sh, Wt_tsp,  768, WtbT);

    // -------- MFMA projections (K-split x2 partials into P) --------
    gemm_mfma<<<dim3((ITEMN + 63) / 64, 2), 256, 0, stream>>>(img, ITEMN, 4096, WtbI, P, 0, 2);
    gemm_mfma<<<dim3((ITEMN + 63) / 64, 2), 256, 0, stream>>>(txt, ITEMN,  768, WtbT, P, 1, 3);

    // -------- X1b = bf16([uE ; l2norm(A@W+b)]); X2b item rows = bf16(iE) --------
    build_feats<<<NN, 256, 0, stream>>>(P, u_sh, u_vsp, u_tsp, i_sh, i_vsp, i_tsp,
                                        bi_sh, bt_sh, bi_vsp, bt_tsp, X1b, X2b);

    // -------- pass1: E1b = bf16(adj @ X1b); X2b user rows = E1b --------
    spmm_e1<<<waveBlocks, 256, 0, stream>>>(rpA, evA, X1b, E1b, X2b);

    // -------- out = E1b + adj@X2b --------
    fused_comb_main<<<waveBlocks, 256, 0, stream>>>(rpA, evA, X2b, E1b, out);

    // -------- out += LAM*modal; OUTb = bf16(out) --------
    modal_add<<<modalBlocks, 256, 0, stream>>>(rpI, evI, rpT, evT, X1b, X2b, out, OUTb);

    // -------- layer1: C1b = bf16(adj @ OUTb) --------
    spmm_l1<<<waveBlocks, 256, 0, stream>>>(rpA, evA, OUTb, C1b);

    // -------- layer2 + final: out += C1b + adj@C1b --------
    fused_final<<<waveBlocks, 256, 0, stream>>>(rpA, evA, C1b, out);
}

// Round 8
// 1132.742 us; speedup vs baseline: 1.1233x; 1.1233x over previous
//
#include <hip/hip_runtime.h>

#define USERN 50000
#define ITEMN 20000
#define NN    70000
#define DTOT  256        // 4 branches x 64
#define LAMv  0.2f
#define E_MAINN  2000000
#define E_MODALN 1000000
#define B1    64         // coarse buckets
#define RPB1  1094       // rows per bucket: 64*1094 = 70016 >= 70000
#define CAP   96         // LDS entries per bucket in radix_a
#define FLUSH 64         // flush chunk (512 B)
#define NBLK1 128
#define SPAN  5          // ceil(RPB1/256)

typedef float  v4f  __attribute__((ext_vector_type(4)));
typedef float  v8f  __attribute__((ext_vector_type(8)));
typedef short  v8s  __attribute__((ext_vector_type(8)));
typedef unsigned short v8u __attribute__((ext_vector_type(8)));

// ---------- bf16 helpers ----------
__device__ inline unsigned short f2bf(float f) {           // RNE
    unsigned u = __float_as_uint(f);
    u += 0x7FFFu + ((u >> 16) & 1u);
    return (unsigned short)(u >> 16);
}
__device__ inline v8f bf8f(v8u u) {
    v8f f;
    #pragma unroll
    for (int i = 0; i < 8; ++i) f[i] = __uint_as_float((unsigned)u[i] << 16);
    return f;
}
__device__ inline v8u f8bf(v8f f) {
    v8u u;
    #pragma unroll
    for (int i = 0; i < 8; ++i) u[i] = f2bf(f[i]);
    return u;
}
__device__ inline ushort4 f4bf(float4 f) {
    return make_ushort4(f2bf(f.x), f2bf(f.y), f2bf(f.z), f2bf(f.w));
}

__device__ inline int wave_incl_scan64(int x, int lane) {
    #pragma unroll
    for (int off = 1; off < 64; off <<= 1) {
        int t = __shfl_up(x, off, 64);
        if (lane >= off) x += t;
    }
    return x;
}

// ---------------- W transpose+cvt: Wtb[c][k], c<64 from W0 else W1 -------------------------
__global__ __launch_bounds__(256) void wt_build(
    const float* __restrict__ W0, const float* __restrict__ W1, int K,
    unsigned short* __restrict__ Wtb)
{
    int idx = blockIdx.x * 256 + threadIdx.x;
    if (idx >= 128 * K) return;
    int c = idx / K, k = idx - c * K;
    float v = (c < 64) ? W0[(size_t)k * 64 + c] : W1[(size_t)k * 64 + (c - 64)];
    Wtb[idx] = f2bf(v);
}

// ---------------- MFMA GEMM: P[seg][M][256] partials, K-split x2 ---------------------------
#define LDK 40   // padded k-stride in LDS (80B rows -> conflict-free b128)

__global__ __launch_bounds__(256) void gemm_mfma(
    const float* __restrict__ A, int M, int K,
    const unsigned short* __restrict__ Wtb,
    float* __restrict__ P, int blkA, int blkB)
{
    __shared__ __align__(16) unsigned short As[64 * LDK];
    __shared__ __align__(16) unsigned short Ws[128 * LDK];
    const int tid  = threadIdx.x;
    const int row0 = blockIdx.x * 64;
    const int segLen = K >> 1;
    const int k0   = blockIdx.y * segLen;
    const int kend = k0 + segLen;
    float* outP = P + (size_t)blockIdx.y * ITEMN * DTOT;

    const int w   = tid >> 6;
    const int l   = tid & 63;
    const int l16 = l & 15, kg = l >> 4;

    const int sar = tid >> 2, sak = (tid & 3) * 8;
    const int swc = tid >> 1, swk = (tid & 1) * 16;

    v4f acc[8];
    #pragma unroll
    for (int n = 0; n < 8; ++n) acc[n] = (v4f)0.f;

    for (int kt = k0; kt < kend; kt += 32) {
        __syncthreads();
        {
            int arow = row0 + sar; if (arow >= M) arow = M - 1;
            const float* ap = A + (size_t)arow * K + kt + sak;
            float4 a0 = ((const float4*)ap)[0];
            float4 a1 = ((const float4*)ap)[1];
            *(ushort4*)&As[sar * LDK + sak]     = f4bf(a0);
            *(ushort4*)&As[sar * LDK + sak + 4] = f4bf(a1);
            const unsigned short* wp = Wtb + (size_t)swc * K + kt + swk;
            *(uint4*)&Ws[swc * LDK + swk]     = ((const uint4*)wp)[0];
            *(uint4*)&Ws[swc * LDK + swk + 8] = ((const uint4*)wp)[1];
        }
        __syncthreads();

        v8s af = *(const v8s*)&As[(w * 16 + l16) * LDK + kg * 8];
        #pragma unroll
        for (int n = 0; n < 8; ++n) {
            v8s bf = *(const v8s*)&Ws[(n * 16 + l16) * LDK + kg * 8];
            acc[n] = __builtin_amdgcn_mfma_f32_16x16x32_bf16(af, bf, acc[n], 0, 0, 0);
        }
    }

    #pragma unroll
    for (int n = 0; n < 8; ++n) {
        const int col  = n * 16 + l16;
        const int gcol = (col < 64) ? blkA * 64 + col : blkB * 64 + (col - 64);
        #pragma unroll
        for (int r = 0; r < 4; ++r) {
            int row = row0 + w * 16 + kg * 4 + r;
            if (row < M) outP[(size_t)row * DTOT + gcol] = acc[n][r];
        }
    }
}

// ------- build feats: X1b user=uE, item=l2norm(P-reduce+bias); X2b item=iE ----------------
__global__ __launch_bounds__(256) void build_feats(
    const float* __restrict__ P,
    const float* __restrict__ u_sh, const float* __restrict__ u_vsp, const float* __restrict__ u_tsp,
    const float* __restrict__ i_sh, const float* __restrict__ i_vsp, const float* __restrict__ i_tsp,
    const float* __restrict__ bi_sh, const float* __restrict__ bt_sh,
    const float* __restrict__ bi_vsp, const float* __restrict__ bt_tsp,
    unsigned short* __restrict__ X1b, unsigned short* __restrict__ X2b)
{
    const int n = blockIdx.x;
    const int t = threadIdx.x;
    const int b = t >> 6, k = t & 63;
    if (n < USERN) {
        const float* u = (b < 2) ? u_sh : (b == 2 ? u_vsp : u_tsp);
        X1b[(size_t)n * DTOT + t] = f2bf(u[(size_t)n * 64 + k]);
    } else {
        const int it = n - USERN;
        const size_t SEG = (size_t)ITEMN * DTOT;
        size_t idx = (size_t)it * DTOT + t;
        float f = P[idx] + P[idx + SEG];
        const float* bias = (b == 0) ? bi_sh : (b == 1 ? bt_sh : (b == 2 ? bi_vsp : bt_tsp));
        f += bias[k];
        float s = f * f;
        #pragma unroll
        for (int off = 32; off > 0; off >>= 1) s += __shfl_xor(s, off, 64);
        X1b[(size_t)n * DTOT + t] = f2bf(f / fmaxf(sqrtf(s), 1e-12f));
        const float* p = (b < 2) ? i_sh : (b == 2 ? i_vsp : i_tsp);
        X2b[(size_t)n * DTOT + t] = f2bf(p[(size_t)it * 64 + k]);
    }
}

// ---------------- CSR build: coarse count, bases, LDS-chunked radix, per-bucket sort -------
__global__ __launch_bounds__(256) void bucket_count(
    const int* __restrict__ ar, const int* __restrict__ mir, const int* __restrict__ mtr,
    int* __restrict__ bcount)
{
    const int g = blockIdx.y;
    const int* rows = (g == 0) ? ar : (g == 1 ? mir : mtr);
    const int E = (g == 0) ? E_MAINN : E_MODALN;
    __shared__ int h[B1];
    if (threadIdx.x < B1) h[threadIdx.x] = 0;
    __syncthreads();
    const int chunk = (E + gridDim.x - 1) / gridDim.x;
    const int c0 = blockIdx.x * chunk, c1 = min(c0 + chunk, E);
    for (int i = c0 + threadIdx.x; i < c1; i += 256)
        atomicAdd(&h[rows[i] / RPB1], 1);
    __syncthreads();
    if (threadIdx.x < B1 && h[threadIdx.x])
        atomicAdd(&bcount[g * B1 + threadIdx.x], h[threadIdx.x]);
}

__global__ __launch_bounds__(256) void bucket_base(
    const int* __restrict__ bcount, int* __restrict__ gbase, int* __restrict__ gcnt)
{
    const int g = threadIdx.x >> 6, lane = threadIdx.x & 63;
    if (g < 3) {
        int v = bcount[g * B1 + lane];
        int x = wave_incl_scan64(v, lane);
        gbase[g * (B1 + 1) + lane] = x - v;
        if (lane == 63) gbase[g * (B1 + 1) + B1] = x;
        gcnt[g * B1 + lane] = 0;
    }
}

// Pass A: stage edges per coarse bucket in LDS, flush full 512B chunks (merged writes).
// entry: x = rl(11b)<<17 | col(17b), y = f32 val bits.
__global__ __launch_bounds__(256) void radix_a(
    const int* __restrict__ ar,  const int* __restrict__ ac,  const float* __restrict__ av,
    const int* __restrict__ mir, const int* __restrict__ mic, const float* __restrict__ miv,
    const int* __restrict__ mtr, const int* __restrict__ mtc, const float* __restrict__ mtv,
    const int* __restrict__ gbase, int* __restrict__ gcnt,
    uint2* __restrict__ tmpA, uint2* __restrict__ tmpI, uint2* __restrict__ tmpT)
{
    const int g = blockIdx.y;
    const int* rows   = (g == 0) ? ar : (g == 1 ? mir : mtr);
    const int* cols   = (g == 0) ? ac : (g == 1 ? mic : mtc);
    const float* vals = (g == 0) ? av : (g == 1 ? miv : mtv);
    uint2* tmp        = (g == 0) ? tmpA : (g == 1 ? tmpI : tmpT);
    const int E = (g == 0) ? E_MAINN : E_MODALN;
    const int* gb = gbase + g * (B1 + 1);
    int* gc = gcnt + g * B1;

    __shared__ uint2 buf[B1][CAP];
    __shared__ int bcnt_s[B1];
    const int tid = threadIdx.x;
    if (tid < B1) bcnt_s[tid] = 0;
    __syncthreads();

    const int chunk = (E + gridDim.x - 1) / gridDim.x;
    const int c0 = blockIdx.x * chunk, c1 = min(c0 + chunk, E);
    const int b = tid >> 2, sub = tid & 3;
    const int blane = (tid & 63) & ~3;

    for (int base = c0; base < c1; base += 256) {
        int i = base + tid;
        if (i < c1) {
            int r = rows[i];
            int b1 = r / RPB1;
            int rl = r - b1 * RPB1;
            uint2 entry = make_uint2(((unsigned)rl << 17) | (unsigned)cols[i],
                                     __float_as_uint(vals[i]));
            int slot = atomicAdd(&bcnt_s[b1], 1);
            if (slot < CAP) buf[b1][slot] = entry;
            else tmp[gb[b1] + atomicAdd(&gc[b1], 1)] = entry;   // overflow (≈never)
        }
        __syncthreads();
        int bc = min(bcnt_s[b], CAP);
        if (bc >= FLUSH) {
            int goff = 0;
            if (sub == 0) goff = gb[b] + atomicAdd(&gc[b], FLUSH);
            goff = __shfl(goff, blane, 64);
            for (int t = sub; t < FLUSH; t += 4)
                tmp[goff + t] = buf[b][t];
            int rem = bc - FLUSH;
            for (int t = sub; t < rem; t += 4)
                buf[b][t] = buf[b][FLUSH + t];
            if (sub == 0) bcnt_s[b] = rem;
        }
        __syncthreads();
    }
    // drain remainders
    int bc = min(bcnt_s[b], CAP);
    if (bc > 0) {
        int goff = 0;
        if (sub == 0) goff = gb[b] + atomicAdd(&gc[b], bc);
        goff = __shfl(goff, blane, 64);
        for (int t = sub; t < bc; t += 4)
            tmp[goff + t] = buf[b][t];
    }
}

// Pass B: per coarse bucket: LDS row-histogram -> scan -> write rp -> scatter to final ev.
__global__ __launch_bounds__(256) void bucket_sort(
    const int* __restrict__ gbase,
    const uint2* __restrict__ tmp, uint2* __restrict__ ev, int* __restrict__ rp, int gidx)
{
    const int b1 = blockIdx.x;
    const int r0 = b1 * RPB1;
    const int r1 = min(r0 + RPB1, NN);
    const int nr = r1 - r0;
    const int gb = gbase[gidx * (B1 + 1) + b1];
    const int count = gbase[gidx * (B1 + 1) + b1 + 1] - gb;
    __shared__ int lcnt[RPB1];
    __shared__ int lrp[RPB1];
    __shared__ int wsum[4];
    const int tid = threadIdx.x, lane = tid & 63, wv = tid >> 6;
    for (int t = tid; t < nr; t += 256) lcnt[t] = 0;
    __syncthreads();
    for (int t = tid; t < count; t += 256)
        atomicAdd(&lcnt[tmp[gb + t].x >> 17], 1);
    __syncthreads();
    // scan over nr counters (thread t owns rows [t*SPAN, t*SPAN+SPAN))
    int loc[SPAN]; int s = 0;
    #pragma unroll
    for (int j = 0; j < SPAN; ++j) {
        int idx = tid * SPAN + j;
        int v = (idx < nr) ? lcnt[idx] : 0;
        loc[j] = s; s += v;
    }
    int x = wave_incl_scan64(s, lane);
    if (lane == 63) wsum[wv] = x;
    __syncthreads();
    int woff = 0;
    for (int i = 0; i < wv; ++i) woff += wsum[i];
    int ex = woff + x - s;
    #pragma unroll
    for (int j = 0; j < SPAN; ++j) {
        int idx = tid * SPAN + j;
        if (idx < nr) lrp[idx] = gb + ex + loc[j];
    }
    __syncthreads();
    for (int t = tid; t < nr; t += 256) rp[r0 + t] = lrp[t];
    if (tid == 0 && r1 == NN) rp[NN] = gb + count;
    __syncthreads();
    // scatter; lrp doubles as the per-row position allocator
    int t = tid;
    for (; t + 768 < count; t += 1024) {
        uint2 q0 = tmp[gb + t];
        uint2 q1 = tmp[gb + t + 256];
        uint2 q2 = tmp[gb + t + 512];
        uint2 q3 = tmp[gb + t + 768];
        int p0 = atomicAdd(&lrp[q0.x >> 17], 1);
        int p1 = atomicAdd(&lrp[q1.x >> 17], 1);
        int p2 = atomicAdd(&lrp[q2.x >> 17], 1);
        int p3 = atomicAdd(&lrp[q3.x >> 17], 1);
        ev[p0] = make_uint2(q0.x & 0x1FFFFu, q0.y);
        ev[p1] = make_uint2(q1.x & 0x1FFFFu, q1.y);
        ev[p2] = make_uint2(q2.x & 0x1FFFFu, q2.y);
        ev[p3] = make_uint2(q3.x & 0x1FFFFu, q3.y);
    }
    for (; t < count; t += 256) {
        uint2 q = tmp[gb + t];
        int p = atomicAdd(&lrp[q.x >> 17], 1);
        ev[p] = make_uint2(q.x & 0x1FFFFu, q.y);
    }
}

// -------- CSR SpMM: wave/row, half-wave per edge, 16B lanes, 8 edges in flight -------------
#define SPMM8_HEAD                                                                  \
    const int w = (blockIdx.x * blockDim.x + threadIdx.x) >> 6;                     \
    if (w >= NN) return;                                                            \
    const int lane = threadIdx.x & 63;                                              \
    const int half = lane >> 5, l5 = lane & 31;                                     \
    const v8u* __restrict__ Xv = (const v8u*)Xb;                                    \
    int e = rp[w]; const int end = rp[w + 1];                                       \
    v8f acc = (v8f)0.f;                                                             \
    for (; e + 8 <= end; e += 8) {                                                  \
        uint2 q0 = ev[e + half],     q1 = ev[e + 2 + half];                         \
        uint2 q2 = ev[e + 4 + half], q3 = ev[e + 6 + half];                         \
        v8f g0 = bf8f(Xv[(size_t)q0.x * 32 + l5]);                                  \
        v8f g1 = bf8f(Xv[(size_t)q1.x * 32 + l5]);                                  \
        v8f g2 = bf8f(Xv[(size_t)q2.x * 32 + l5]);                                  \
        v8f g3 = bf8f(Xv[(size_t)q3.x * 32 + l5]);                                  \
        float v0 = __uint_as_float(q0.y), v1 = __uint_as_float(q1.y);               \
        float v2 = __uint_as_float(q2.y), v3 = __uint_as_float(q3.y);               \
        _Pragma("unroll")                                                           \
        for (int i = 0; i < 8; ++i) {                                               \
            acc[i] = fmaf(v0, g0[i], acc[i]); acc[i] = fmaf(v1, g1[i], acc[i]);     \
            acc[i] = fmaf(v2, g2[i], acc[i]); acc[i] = fmaf(v3, g3[i], acc[i]);     \
        }                                                                           \
    }                                                                               \
    for (; e + 2 <= end; e += 2) {                                                  \
        uint2 q = ev[e + half];                                                     \
        v8f g = bf8f(Xv[(size_t)q.x * 32 + l5]);                                    \
        float v = __uint_as_float(q.y);                                             \
        _Pragma("unroll")                                                           \
        for (int i = 0; i < 8; ++i) acc[i] = fmaf(v, g[i], acc[i]);                 \
    }                                                                               \
    if (e < end && half == 0) {                                                     \
        uint2 q = ev[e];                                                            \
        v8f g = bf8f(Xv[(size_t)q.x * 32 + l5]);                                    \
        float v = __uint_as_float(q.y);                                             \
        _Pragma("unroll")                                                           \
        for (int i = 0; i < 8; ++i) acc[i] = fmaf(v, g[i], acc[i]);                 \
    }                                                                               \
    _Pragma("unroll")                                                               \
    for (int i = 0; i < 8; ++i) acc[i] += __shfl_xor(acc[i], 32, 64);               \
    if (half != 0) return;                                                          \
    const size_t oidx = (size_t)w * DTOT + l5 * 8;

// E1b = bf16(adj @ X1b); X2b user rows = same
__global__ __launch_bounds__(256) void spmm_e1(
    const int* __restrict__ rp, const uint2* __restrict__ ev,
    const unsigned short* __restrict__ Xb, unsigned short* __restrict__ E1b,
    unsigned short* __restrict__ X2b)
{
    SPMM8_HEAD
    v8u ub = f8bf(acc);
    *(v8u*)&E1b[oidx] = ub;
    if (w < USERN) *(v8u*)&X2b[oidx] = ub;
}

// out = E1b + adj @ X2b   (f32 out)
__global__ __launch_bounds__(256) void fused_comb_main(
    const int* __restrict__ rp, const uint2* __restrict__ ev,
    const unsigned short* __restrict__ Xb, const unsigned short* __restrict__ E1b,
    float* __restrict__ out)
{
    SPMM8_HEAD
    v8f o = bf8f(*(const v8u*)&E1b[oidx]);
    #pragma unroll
    for (int i = 0; i < 8; ++i) o[i] += acc[i];
    *(v8f*)&out[oidx] = o;
}

// C1b = bf16(adj @ OUTb)
__global__ __launch_bounds__(256) void spmm_l1(
    const int* __restrict__ rp, const uint2* __restrict__ ev,
    const unsigned short* __restrict__ Xb, unsigned short* __restrict__ C1b)
{
    SPMM8_HEAD
    *(v8u*)&C1b[oidx] = f8bf(acc);
}

// out += C1b + adj @ C1b   (Xb == C1b)
__global__ __launch_bounds__(256) void fused_final(
    const int* __restrict__ rp, const uint2* __restrict__ ev,
    const unsigned short* __restrict__ Xb, float* __restrict__ out)
{
    SPMM8_HEAD
    v8f o = *(const v8f*)&out[oidx];
    v8f c = bf8f(Xv[(size_t)w * 32 + l5]);
    #pragma unroll
    for (int i = 0; i < 8; ++i) o[i] += c[i] + acc[i];
    *(v8f*)&out[oidx] = o;
}

// -------- modal: wave per (row, modality), quarter-wave per edge, 16B lanes ----------------
__global__ __launch_bounds__(256) void modal_add(
    const int* __restrict__ rpI, const uint2* __restrict__ evI,
    const int* __restrict__ rpT, const uint2* __restrict__ evT,
    const unsigned short* __restrict__ X1b, const unsigned short* __restrict__ X2b,
    float* __restrict__ out, unsigned short* __restrict__ OUTb)
{
    const int gw = (blockIdx.x * blockDim.x + threadIdx.x) >> 6;
    if (gw >= 2 * NN) return;
    const int r = gw >> 1, m = gw & 1;
    const int lane = threadIdx.x & 63;
    const int qt = lane >> 4, l4 = lane & 15;
    const int* rp   = m ? rpT : rpI;
    const uint2* ev = m ? evT : evI;
    const int slot = m * 8 + (l4 >> 3) * 16 + (l4 & 7);     // ushort8 slot (blocks m, m+2)
    const v8u* X1v = (const v8u*)X1b;
    const v8u* X2v = (const v8u*)X2b;
    v8f acc = (v8f)0.f;
    int e = rp[r]; const int end = rp[r + 1];
    for (; e + 4 <= end; e += 4) {
        uint2 q = ev[e + qt];
        const v8u* B = ((int)q.x < USERN) ? X1v : X2v;
        v8f g = bf8f(B[(size_t)q.x * 32 + slot]);
        float v = __uint_as_float(q.y) * LAMv;
        #pragma unroll
        for (int i = 0; i < 8; ++i) acc[i] = fmaf(v, g[i], acc[i]);
    }
    if (qt < end - e) {
        uint2 q = ev[e + qt];
        const v8u* B = ((int)q.x < USERN) ? X1v : X2v;
        v8f g = bf8f(B[(size_t)q.x * 32 + slot]);
        float v = __uint_as_float(q.y) * LAMv;
        #pragma unroll
        for (int i = 0; i < 8; ++i) acc[i] = fmaf(v, g[i], acc[i]);
    }
    #pragma unroll
    for (int i = 0; i < 8; ++i) {
        acc[i] += __shfl_xor(acc[i], 16, 64);
        acc[i] += __shfl_xor(acc[i], 32, 64);
    }
    if (lane < 16) {
        const size_t idx = (size_t)r * DTOT + slot * 8;
        v8f o = *(const v8f*)&out[idx];
        #pragma unroll
        for (int i = 0; i < 8; ++i) o[i] += acc[i];
        *(v8f*)&out[idx] = o;
        *(v8u*)&OUTb[idx] = f8bf(o);
    }
}

extern "C" void kernel_launch(void* const* d_in, const int* in_sizes, int n_in,
                              void* d_out, int out_size, void* d_ws, size_t ws_size,
                              hipStream_t stream)
{
    const float* img = (const float*)d_in[0];
    const float* txt = (const float*)d_in[1];
    const int*   ar  = (const int*)d_in[2];
    const int*   ac  = (const int*)d_in[3];
    const float* av  = (const float*)d_in[4];
    const int*   mir = (const int*)d_in[5];
    const int*   mic = (const int*)d_in[6];
    const float* miv = (const float*)d_in[7];
    const int*   mtr = (const int*)d_in[8];
    const int*   mtc = (const int*)d_in[9];
    const float* mtv = (const float*)d_in[10];
    const float* u_sh   = (const float*)d_in[11];
    const float* i_sh   = (const float*)d_in[12];
    const float* Wi_sh  = (const float*)d_in[13];
    const float* bi_sh  = (const float*)d_in[14];
    const float* Wt_sh  = (const float*)d_in[15];
    const float* bt_sh  = (const float*)d_in[16];
    const float* u_vsp  = (const float*)d_in[17];
    const float* i_vsp  = (const float*)d_in[18];
    const float* Wi_vsp = (const float*)d_in[19];
    const float* bi_vsp = (const float*)d_in[20];
    const float* u_tsp  = (const float*)d_in[21];
    const float* i_tsp  = (const float*)d_in[22];
    const float* Wt_tsp = (const float*)d_in[23];
    const float* bt_tsp = (const float*)d_in[24];

    // -------- workspace layout --------
    const size_t NE = (size_t)NN * DTOT;
    unsigned short* X1b  = (unsigned short*)d_ws;        // 35.84 MB
    unsigned short* X2b  = X1b + NE;                     // 35.84 MB
    unsigned short* OUTb = X2b + NE;                     // 35.84 MB
    unsigned short* E1b  = OUTb + NE;                    // 35.84 MB
    unsigned short* C1b  = X1b;                          // alias: X1b dead after modal_add
    float* P = (float*)(E1b + NE);                       // [2][ITEM,256] f32 = 40.96 MB
    unsigned short* WtbI = (unsigned short*)(P + 2 * (size_t)ITEMN * DTOT);  // 1 MB
    unsigned short* WtbT = WtbI + 128 * 4096;
    uint2* evA  = (uint2*)(WtbT + 128 * 768);            // 16 MB
    uint2* evI  = evA + E_MAINN;                         // 8 MB
    uint2* evT  = evI + E_MODALN;                        // 8 MB
    uint2* tmpA = evT + E_MODALN;                        // 16 MB
    uint2* tmpI = tmpA + E_MAINN;                        // 8 MB
    uint2* tmpT = tmpI + E_MODALN;                       // 8 MB
    int*   rpA   = (int*)(tmpT + E_MODALN);              // NN+1 each
    int*   rpI   = rpA + (NN + 4);
    int*   rpT   = rpI + (NN + 4);
    int*   bcount = rpT + (NN + 4);                      // 3*B1
    int*   gbase  = bcount + 3 * B1;                     // 3*(B1+1)
    int*   gcnt   = gbase + 3 * (B1 + 1);                // 3*B1
    float* out   = (float*)d_out;

    const int waveBlocks  = (NN * 64) / 256;             // 17500
    const int modalBlocks = (2 * NN * 64) / 256;         // 35000

    // -------- CSR build (LDS-chunked two-level counting sort) --------
    hipMemsetAsync(bcount, 0, 3 * B1 * sizeof(int), stream);
    bucket_count<<<dim3(NBLK1, 3), 256, 0, stream>>>(ar, mir, mtr, bcount);
    bucket_base<<<1, 256, 0, stream>>>(bcount, gbase, gcnt);
    radix_a<<<dim3(NBLK1, 3), 256, 0, stream>>>(ar, ac, av, mir, mic, miv, mtr, mtc, mtv,
                                                gbase, gcnt, tmpA, tmpI, tmpT);
    bucket_sort<<<B1, 256, 0, stream>>>(gbase, tmpA, evA, rpA, 0);
    bucket_sort<<<B1, 256, 0, stream>>>(gbase, tmpI, evI, rpI, 1);
    bucket_sort<<<B1, 256, 0, stream>>>(gbase, tmpT, evT, rpT, 2);

    // -------- W transpose to bf16 --------
    wt_build<<<(128 * 4096 + 255) / 256, 256, 0, stream>>>(Wi_sh, Wi_vsp, 4096, WtbI);
    wt_build<<<(128 * 768  + 255) / 256, 256, 0, stream>>>(Wt_sh, Wt_tsp,  768, WtbT);

    // -------- MFMA projections (K-split x2 partials into P) --------
    gemm_mfma<<<dim3((ITEMN + 63) / 64, 2), 256, 0, stream>>>(img, ITEMN, 4096, WtbI, P, 0, 2);
    gemm_mfma<<<dim3((ITEMN + 63) / 64, 2), 256, 0, stream>>>(txt, ITEMN,  768, WtbT, P, 1, 3);

    // -------- X1b = bf16([uE ; l2norm(A@W+b)]); X2b item rows = bf16(iE) --------
    build_feats<<<NN, 256, 0, stream>>>(P, u_sh, u_vsp, u_tsp, i_sh, i_vsp, i_tsp,
                                        bi_sh, bt_sh, bi_vsp, bt_tsp, X1b, X2b);

    // -------- pass1: E1b = bf16(adj @ X1b); X2b user rows = E1b --------
    spmm_e1<<<waveBlocks, 256, 0, stream>>>(rpA, evA, X1b, E1b, X2b);

    // -------- out = E1b + adj@X2b --------
    fused_comb_main<<<waveBlocks, 256, 0, stream>>>(rpA, evA, X2b, E1b, out);

    // -------- out += LAM*modal; OUTb = bf16(out) --------
    modal_add<<<modalBlocks, 256, 0, stream>>>(rpI, evI, rpT, evT, X1b, X2b, out, OUTb);

    // -------- layer1: C1b = bf16(adj @ OUTb) --------
    spmm_l1<<<waveBlocks, 256, 0, stream>>>(rpA, evA, OUTb, C1b);

    // -------- layer2 + final: out += C1b + adj@C1b --------
    fused_final<<<waveBlocks, 256, 0, stream>>>(rpA, evA, C1b, out);
}

// Round 9
// 1047.427 us; speedup vs baseline: 1.2148x; 1.0815x over previous
//
#include <hip/hip_runtime.h>

#define USERN 50000
#define ITEMN 20000
#define NN    70000
#define DTOT  256        // 4 branches x 64
#define LAMv  0.2f
#define E_MAINN  2000000
#define E_MODALN 1000000
#define B1    64         // coarse buckets
#define RPB1  1094       // rows per bucket: 64*1094 = 70016 >= 70000
#define CAP   96         // LDS entries per bucket in radix_a
#define FLUSH 64         // flush chunk (512 B)
#define NBLK1 128
#define SPAN  5          // ceil(RPB1/256)

typedef float  v4f  __attribute__((ext_vector_type(4)));
typedef float  v8f  __attribute__((ext_vector_type(8)));
typedef short  v8s  __attribute__((ext_vector_type(8)));
typedef unsigned short v8u __attribute__((ext_vector_type(8)));

// ---------- bf16 helpers ----------
__device__ inline unsigned short f2bf(float f) {           // RNE
    unsigned u = __float_as_uint(f);
    u += 0x7FFFu + ((u >> 16) & 1u);
    return (unsigned short)(u >> 16);
}
__device__ inline v8f bf8f(v8u u) {
    v8f f;
    #pragma unroll
    for (int i = 0; i < 8; ++i) f[i] = __uint_as_float((unsigned)u[i] << 16);
    return f;
}
__device__ inline v8u f8bf(v8f f) {
    v8u u;
    #pragma unroll
    for (int i = 0; i < 8; ++i) u[i] = f2bf(f[i]);
    return u;
}
__device__ inline ushort4 f4bf(float4 f) {
    return make_ushort4(f2bf(f.x), f2bf(f.y), f2bf(f.z), f2bf(f.w));
}

__device__ inline int wave_incl_scan64(int x, int lane) {
    #pragma unroll
    for (int off = 1; off < 64; off <<= 1) {
        int t = __shfl_up(x, off, 64);
        if (lane >= off) x += t;
    }
    return x;
}

// ---------------- W transpose+cvt: Wtb[c][k], c<64 from W0 else W1 -------------------------
__global__ __launch_bounds__(256) void wt_build(
    const float* __restrict__ W0, const float* __restrict__ W1, int K,
    unsigned short* __restrict__ Wtb)
{
    int idx = blockIdx.x * 256 + threadIdx.x;
    if (idx >= 128 * K) return;
    int c = idx / K, k = idx - c * K;
    float v = (c < 64) ? W0[(size_t)k * 64 + c] : W1[(size_t)k * 64 + (c - 64)];
    Wtb[idx] = f2bf(v);
}

// ---------------- MFMA GEMM: P[seg][M][256] partials, K-split x2 ---------------------------
#define LDK 40   // padded k-stride in LDS (80B rows -> conflict-free b128)

__global__ __launch_bounds__(256) void gemm_mfma(
    const float* __restrict__ A, int M, int K,
    const unsigned short* __restrict__ Wtb,
    float* __restrict__ P, int blkA, int blkB)
{
    __shared__ __align__(16) unsigned short As[64 * LDK];
    __shared__ __align__(16) unsigned short Ws[128 * LDK];
    const int tid  = threadIdx.x;
    const int row0 = blockIdx.x * 64;
    const int segLen = K >> 1;
    const int k0   = blockIdx.y * segLen;
    const int kend = k0 + segLen;
    float* outP = P + (size_t)blockIdx.y * ITEMN * DTOT;

    const int w   = tid >> 6;
    const int l   = tid & 63;
    const int l16 = l & 15, kg = l >> 4;

    const int sar = tid >> 2, sak = (tid & 3) * 8;
    const int swc = tid >> 1, swk = (tid & 1) * 16;

    v4f acc[8];
    #pragma unroll
    for (int n = 0; n < 8; ++n) acc[n] = (v4f)0.f;

    for (int kt = k0; kt < kend; kt += 32) {
        __syncthreads();
        {
            int arow = row0 + sar; if (arow >= M) arow = M - 1;
            const float* ap = A + (size_t)arow * K + kt + sak;
            float4 a0 = ((const float4*)ap)[0];
            float4 a1 = ((const float4*)ap)[1];
            *(ushort4*)&As[sar * LDK + sak]     = f4bf(a0);
            *(ushort4*)&As[sar * LDK + sak + 4] = f4bf(a1);
            const unsigned short* wp = Wtb + (size_t)swc * K + kt + swk;
            *(uint4*)&Ws[swc * LDK + swk]     = ((const uint4*)wp)[0];
            *(uint4*)&Ws[swc * LDK + swk + 8] = ((const uint4*)wp)[1];
        }
        __syncthreads();

        v8s af = *(const v8s*)&As[(w * 16 + l16) * LDK + kg * 8];
        #pragma unroll
        for (int n = 0; n < 8; ++n) {
            v8s bf = *(const v8s*)&Ws[(n * 16 + l16) * LDK + kg * 8];
            acc[n] = __builtin_amdgcn_mfma_f32_16x16x32_bf16(af, bf, acc[n], 0, 0, 0);
        }
    }

    #pragma unroll
    for (int n = 0; n < 8; ++n) {
        const int col  = n * 16 + l16;
        const int gcol = (col < 64) ? blkA * 64 + col : blkB * 64 + (col - 64);
        #pragma unroll
        for (int r = 0; r < 4; ++r) {
            int row = row0 + w * 16 + kg * 4 + r;
            if (row < M) outP[(size_t)row * DTOT + gcol] = acc[n][r];
        }
    }
}

// ------- build feats: X1b user=uE, item=l2norm(P-reduce+bias); X2b item=iE ----------------
__global__ __launch_bounds__(256) void build_feats(
    const float* __restrict__ P,
    const float* __restrict__ u_sh, const float* __restrict__ u_vsp, const float* __restrict__ u_tsp,
    const float* __restrict__ i_sh, const float* __restrict__ i_vsp, const float* __restrict__ i_tsp,
    const float* __restrict__ bi_sh, const float* __restrict__ bt_sh,
    const float* __restrict__ bi_vsp, const float* __restrict__ bt_tsp,
    unsigned short* __restrict__ X1b, unsigned short* __restrict__ X2b)
{
    const int n = blockIdx.x;
    const int t = threadIdx.x;
    const int b = t >> 6, k = t & 63;
    if (n < USERN) {
        const float* u = (b < 2) ? u_sh : (b == 2 ? u_vsp : u_tsp);
        X1b[(size_t)n * DTOT + t] = f2bf(u[(size_t)n * 64 + k]);
    } else {
        const int it = n - USERN;
        const size_t SEG = (size_t)ITEMN * DTOT;
        size_t idx = (size_t)it * DTOT + t;
        float f = P[idx] + P[idx + SEG];
        const float* bias = (b == 0) ? bi_sh : (b == 1 ? bt_sh : (b == 2 ? bi_vsp : bt_tsp));
        f += bias[k];
        float s = f * f;
        #pragma unroll
        for (int off = 32; off > 0; off >>= 1) s += __shfl_xor(s, off, 64);
        X1b[(size_t)n * DTOT + t] = f2bf(f / fmaxf(sqrtf(s), 1e-12f));
        const float* p = (b < 2) ? i_sh : (b == 2 ? i_vsp : i_tsp);
        X2b[(size_t)n * DTOT + t] = f2bf(p[(size_t)it * 64 + k]);
    }
}

// ---------------- CSR build: coarse count, bases, LDS-chunked radix, per-bucket sort -------
__global__ __launch_bounds__(256) void bucket_count(
    const int* __restrict__ ar, const int* __restrict__ mir, const int* __restrict__ mtr,
    int* __restrict__ bcount)
{
    const int g = blockIdx.y;
    const int* rows = (g == 0) ? ar : (g == 1 ? mir : mtr);
    const int E = (g == 0) ? E_MAINN : E_MODALN;
    __shared__ int h[B1];
    if (threadIdx.x < B1) h[threadIdx.x] = 0;
    __syncthreads();
    const int chunk = (E + gridDim.x - 1) / gridDim.x;
    const int c0 = blockIdx.x * chunk, c1 = min(c0 + chunk, E);
    for (int i = c0 + threadIdx.x; i < c1; i += 256)
        atomicAdd(&h[rows[i] / RPB1], 1);
    __syncthreads();
    if (threadIdx.x < B1 && h[threadIdx.x])
        atomicAdd(&bcount[g * B1 + threadIdx.x], h[threadIdx.x]);
}

__global__ __launch_bounds__(256) void bucket_base(
    const int* __restrict__ bcount, int* __restrict__ gbase, int* __restrict__ gcnt)
{
    const int g = threadIdx.x >> 6, lane = threadIdx.x & 63;
    if (g < 3) {
        int v = bcount[g * B1 + lane];
        int x = wave_incl_scan64(v, lane);
        gbase[g * (B1 + 1) + lane] = x - v;
        if (lane == 63) gbase[g * (B1 + 1) + B1] = x;
        gcnt[g * B1 + lane] = 0;
    }
}

// Pass A: stage edges per coarse bucket in LDS, flush full 512B chunks (merged writes).
// entry: x = rl(11b)<<17 | col(17b), y = f32 val bits.
__global__ __launch_bounds__(256) void radix_a(
    const int* __restrict__ ar,  const int* __restrict__ ac,  const float* __restrict__ av,
    const int* __restrict__ mir, const int* __restrict__ mic, const float* __restrict__ miv,
    const int* __restrict__ mtr, const int* __restrict__ mtc, const float* __restrict__ mtv,
    const int* __restrict__ gbase, int* __restrict__ gcnt,
    uint2* __restrict__ tmpA, uint2* __restrict__ tmpI, uint2* __restrict__ tmpT)
{
    const int g = blockIdx.y;
    const int* rows   = (g == 0) ? ar : (g == 1 ? mir : mtr);
    const int* cols   = (g == 0) ? ac : (g == 1 ? mic : mtc);
    const float* vals = (g == 0) ? av : (g == 1 ? miv : mtv);
    uint2* tmp        = (g == 0) ? tmpA : (g == 1 ? tmpI : tmpT);
    const int E = (g == 0) ? E_MAINN : E_MODALN;
    const int* gb = gbase + g * (B1 + 1);
    int* gc = gcnt + g * B1;

    __shared__ uint2 buf[B1][CAP];
    __shared__ int bcnt_s[B1];
    const int tid = threadIdx.x;
    if (tid < B1) bcnt_s[tid] = 0;
    __syncthreads();

    const int chunk = (E + gridDim.x - 1) / gridDim.x;
    const int c0 = blockIdx.x * chunk, c1 = min(c0 + chunk, E);
    const int b = tid >> 2, sub = tid & 3;
    const int blane = (tid & 63) & ~3;

    for (int base = c0; base < c1; base += 256) {
        int i = base + tid;
        if (i < c1) {
            int r = rows[i];
            int b1 = r / RPB1;
            int rl = r - b1 * RPB1;
            uint2 entry = make_uint2(((unsigned)rl << 17) | (unsigned)cols[i],
                                     __float_as_uint(vals[i]));
            int slot = atomicAdd(&bcnt_s[b1], 1);
            if (slot < CAP) buf[b1][slot] = entry;
            else tmp[gb[b1] + atomicAdd(&gc[b1], 1)] = entry;   // overflow (≈never)
        }
        __syncthreads();
        int bc = min(bcnt_s[b], CAP);
        if (bc >= FLUSH) {
            int goff = 0;
            if (sub == 0) goff = gb[b] + atomicAdd(&gc[b], FLUSH);
            goff = __shfl(goff, blane, 64);
            for (int t = sub; t < FLUSH; t += 4)
                tmp[goff + t] = buf[b][t];
            int rem = bc - FLUSH;
            for (int t = sub; t < rem; t += 4)
                buf[b][t] = buf[b][FLUSH + t];
            if (sub == 0) bcnt_s[b] = rem;
        }
        __syncthreads();
    }
    // drain remainders
    int bc = min(bcnt_s[b], CAP);
    if (bc > 0) {
        int goff = 0;
        if (sub == 0) goff = gb[b] + atomicAdd(&gc[b], bc);
        goff = __shfl(goff, blane, 64);
        for (int t = sub; t < bc; t += 4)
            tmp[goff + t] = buf[b][t];
    }
}

// Pass B: per coarse bucket: LDS row-histogram -> scan -> write rp -> scatter to final ev.
// One launch, grid (B1, 3).
__global__ __launch_bounds__(256) void bucket_sort(
    const int* __restrict__ gbase,
    const uint2* __restrict__ tmpA, const uint2* __restrict__ tmpI, const uint2* __restrict__ tmpT,
    uint2* __restrict__ evA, uint2* __restrict__ evI, uint2* __restrict__ evT,
    int* __restrict__ rpA, int* __restrict__ rpI, int* __restrict__ rpT)
{
    const int gidx = blockIdx.y;
    const uint2* tmp = (gidx == 0) ? tmpA : (gidx == 1 ? tmpI : tmpT);
    uint2* ev        = (gidx == 0) ? evA  : (gidx == 1 ? evI  : evT);
    int* rp          = (gidx == 0) ? rpA  : (gidx == 1 ? rpI  : rpT);
    const int b1 = blockIdx.x;
    const int r0 = b1 * RPB1;
    const int r1 = min(r0 + RPB1, NN);
    const int nr = r1 - r0;
    const int gb = gbase[gidx * (B1 + 1) + b1];
    const int count = gbase[gidx * (B1 + 1) + b1 + 1] - gb;
    __shared__ int lcnt[RPB1];
    __shared__ int lrp[RPB1];
    __shared__ int wsum[4];
    const int tid = threadIdx.x, lane = tid & 63, wv = tid >> 6;
    for (int t = tid; t < nr; t += 256) lcnt[t] = 0;
    __syncthreads();
    for (int t = tid; t < count; t += 256)
        atomicAdd(&lcnt[tmp[gb + t].x >> 17], 1);
    __syncthreads();
    int loc[SPAN]; int s = 0;
    #pragma unroll
    for (int j = 0; j < SPAN; ++j) {
        int idx = tid * SPAN + j;
        int v = (idx < nr) ? lcnt[idx] : 0;
        loc[j] = s; s += v;
    }
    int x = wave_incl_scan64(s, lane);
    if (lane == 63) wsum[wv] = x;
    __syncthreads();
    int woff = 0;
    for (int i = 0; i < wv; ++i) woff += wsum[i];
    int ex = woff + x - s;
    #pragma unroll
    for (int j = 0; j < SPAN; ++j) {
        int idx = tid * SPAN + j;
        if (idx < nr) lrp[idx] = gb + ex + loc[j];
    }
    __syncthreads();
    for (int t = tid; t < nr; t += 256) rp[r0 + t] = lrp[t];
    if (tid == 0 && r1 == NN) rp[NN] = gb + count;
    __syncthreads();
    int t = tid;
    for (; t + 768 < count; t += 1024) {
        uint2 q0 = tmp[gb + t];
        uint2 q1 = tmp[gb + t + 256];
        uint2 q2 = tmp[gb + t + 512];
        uint2 q3 = tmp[gb + t + 768];
        int p0 = atomicAdd(&lrp[q0.x >> 17], 1);
        int p1 = atomicAdd(&lrp[q1.x >> 17], 1);
        int p2 = atomicAdd(&lrp[q2.x >> 17], 1);
        int p3 = atomicAdd(&lrp[q3.x >> 17], 1);
        ev[p0] = make_uint2(q0.x & 0x1FFFFu, q0.y);
        ev[p1] = make_uint2(q1.x & 0x1FFFFu, q1.y);
        ev[p2] = make_uint2(q2.x & 0x1FFFFu, q2.y);
        ev[p3] = make_uint2(q3.x & 0x1FFFFu, q3.y);
    }
    for (; t < count; t += 256) {
        uint2 q = tmp[gb + t];
        int p = atomicAdd(&lrp[q.x >> 17], 1);
        ev[p] = make_uint2(q.x & 0x1FFFFu, q.y);
    }
}

// -------- CSR SpMM: wave/row, half-wave per edge, 16B lanes, 8 edges in flight -------------
#define SPMM8_BODY(RP, EV)                                                          \
    {                                                                               \
        int e = RP[w]; const int end = RP[w + 1];                                   \
        for (; e + 8 <= end; e += 8) {                                              \
            uint2 q0 = EV[e + half],     q1 = EV[e + 2 + half];                     \
            uint2 q2 = EV[e + 4 + half], q3 = EV[e + 6 + half];                     \
            v8f g0 = bf8f(Xv[(size_t)q0.x * 32 + l5]);                              \
            v8f g1 = bf8f(Xv[(size_t)q1.x * 32 + l5]);                              \
            v8f g2 = bf8f(Xv[(size_t)q2.x * 32 + l5]);                              \
            v8f g3 = bf8f(Xv[(size_t)q3.x * 32 + l5]);                              \
            float v0 = __uint_as_float(q0.y), v1 = __uint_as_float(q1.y);           \
            float v2 = __uint_as_float(q2.y), v3 = __uint_as_float(q3.y);           \
            _Pragma("unroll")                                                       \
            for (int i = 0; i < 8; ++i) {                                           \
                acc[i] = fmaf(v0, g0[i], acc[i]); acc[i] = fmaf(v1, g1[i], acc[i]); \
                acc[i] = fmaf(v2, g2[i], acc[i]); acc[i] = fmaf(v3, g3[i], acc[i]); \
            }                                                                       \
        }                                                                           \
        for (; e + 2 <= end; e += 2) {                                              \
            uint2 q = EV[e + half];                                                 \
            v8f g = bf8f(Xv[(size_t)q.x * 32 + l5]);                                \
            float v = __uint_as_float(q.y);                                         \
            _Pragma("unroll")                                                       \
            for (int i = 0; i < 8; ++i) acc[i] = fmaf(v, g[i], acc[i]);             \
        }                                                                           \
        if (e < end && half == 0) {                                                 \
            uint2 q = EV[e];                                                        \
            v8f g = bf8f(Xv[(size_t)q.x * 32 + l5]);                                \
            float v = __uint_as_float(q.y);                                         \
            _Pragma("unroll")                                                       \
            for (int i = 0; i < 8; ++i) acc[i] = fmaf(v, g[i], acc[i]);             \
        }                                                                           \
    }

#define SPMM8_HEAD                                                                  \
    const int w = (blockIdx.x * blockDim.x + threadIdx.x) >> 6;                     \
    if (w >= NN) return;                                                            \
    const int lane = threadIdx.x & 63;                                              \
    const int half = lane >> 5, l5 = lane & 31;                                     \
    const v8u* __restrict__ Xv = (const v8u*)Xb;                                    \
    v8f acc = (v8f)0.f;                                                             \
    SPMM8_BODY(rp, ev)                                                              \
    _Pragma("unroll")                                                               \
    for (int i = 0; i < 8; ++i) acc[i] += __shfl_xor(acc[i], 32, 64);               \
    if (half != 0) return;                                                          \
    const size_t oidx = (size_t)w * DTOT + l5 * 8;

// E1b = bf16(adj @ X1b); X2b user rows = same
__global__ __launch_bounds__(256) void spmm_e1(
    const int* __restrict__ rp, const uint2* __restrict__ ev,
    const unsigned short* __restrict__ Xb, unsigned short* __restrict__ E1b,
    unsigned short* __restrict__ X2b)
{
    SPMM8_HEAD
    v8u ub = f8bf(acc);
    *(v8u*)&E1b[oidx] = ub;
    if (w < USERN) *(v8u*)&X2b[oidx] = ub;
}

// C1b = bf16(adj @ OUTb)
__global__ __launch_bounds__(256) void spmm_l1(
    const int* __restrict__ rp, const uint2* __restrict__ ev,
    const unsigned short* __restrict__ Xb, unsigned short* __restrict__ C1b)
{
    SPMM8_HEAD
    *(v8u*)&C1b[oidx] = f8bf(acc);
}

// out = OUTb + C1b + adj @ C1b   (f32, single final write of d_out)
__global__ __launch_bounds__(256) void fused_final(
    const int* __restrict__ rp, const uint2* __restrict__ ev,
    const unsigned short* __restrict__ Xb, const unsigned short* __restrict__ OUTb,
    float* __restrict__ out)
{
    SPMM8_HEAD
    v8f t = bf8f(*(const v8u*)&OUTb[oidx]);
    v8f c = bf8f(Xv[(size_t)w * 32 + l5]);
    #pragma unroll
    for (int i = 0; i < 8; ++i) t[i] += c[i] + acc[i];
    *(v8f*)&out[oidx] = t;
}

// -------- comb_all: OUTb = bf16(E1b + adj@X2b + LAM*(img modal) + LAM*(txt modal)) ---------
// wave per row: adj via half-wave scheme (slot = l5), modal via quarter-wave scheme.
__global__ __launch_bounds__(256) void comb_all(
    const int* __restrict__ rpA, const uint2* __restrict__ evA,
    const int* __restrict__ rpI, const uint2* __restrict__ evI,
    const int* __restrict__ rpT, const uint2* __restrict__ evT,
    const unsigned short* __restrict__ X1b, const unsigned short* __restrict__ X2b,
    const unsigned short* __restrict__ E1b, unsigned short* __restrict__ OUTb)
{
    const int w = (blockIdx.x * blockDim.x + threadIdx.x) >> 6;
    if (w >= NN) return;
    const int lane = threadIdx.x & 63;
    const int half = lane >> 5, l5 = lane & 31;
    const int qt = lane >> 4, l4 = lane & 15;
    const v8u* __restrict__ X1v = (const v8u*)X1b;
    const v8u* __restrict__ X2v = (const v8u*)X2b;

    // ---- modal img: slots (l4>>3)*16 + (l4&7)  (blocks 0,2) ----
    v8f accI = (v8f)0.f, accT = (v8f)0.f;
    {
        const int slot = (l4 >> 3) * 16 + (l4 & 7);
        int e = rpI[w]; const int end = rpI[w + 1];
        for (; e + 4 <= end; e += 4) {
            uint2 q = evI[e + qt];
            const v8u* B = ((int)q.x < USERN) ? X1v : X2v;
            v8f g = bf8f(B[(size_t)q.x * 32 + slot]);
            float v = __uint_as_float(q.y) * LAMv;
            #pragma unroll
            for (int i = 0; i < 8; ++i) accI[i] = fmaf(v, g[i], accI[i]);
        }
        if (qt < end - e) {
            uint2 q = evI[e + qt];
            const v8u* B = ((int)q.x < USERN) ? X1v : X2v;
            v8f g = bf8f(B[(size_t)q.x * 32 + slot]);
            float v = __uint_as_float(q.y) * LAMv;
            #pragma unroll
            for (int i = 0; i < 8; ++i) accI[i] = fmaf(v, g[i], accI[i]);
        }
    }
    // ---- modal txt: slots 8 + (l4>>3)*16 + (l4&7)  (blocks 1,3) ----
    {
        const int slot = 8 + (l4 >> 3) * 16 + (l4 & 7);
        int e = rpT[w]; const int end = rpT[w + 1];
        for (; e + 4 <= end; e += 4) {
            uint2 q = evT[e + qt];
            const v8u* B = ((int)q.x < USERN) ? X1v : X2v;
            v8f g = bf8f(B[(size_t)q.x * 32 + slot]);
            float v = __uint_as_float(q.y) * LAMv;
            #pragma unroll
            for (int i = 0; i < 8; ++i) accT[i] = fmaf(v, g[i], accT[i]);
        }
        if (qt < end - e) {
            uint2 q = evT[e + qt];
            const v8u* B = ((int)q.x < USERN) ? X1v : X2v;
            v8f g = bf8f(B[(size_t)q.x * 32 + slot]);
            float v = __uint_as_float(q.y) * LAMv;
            #pragma unroll
            for (int i = 0; i < 8; ++i) accT[i] = fmaf(v, g[i], accT[i]);
        }
    }
    // reduce over the 4 quarter groups (every lane ends with its l4-group total)
    #pragma unroll
    for (int i = 0; i < 8; ++i) {
        accI[i] += __shfl_xor(accI[i], 16, 64);
        accI[i] += __shfl_xor(accI[i], 32, 64);
        accT[i] += __shfl_xor(accT[i], 16, 64);
        accT[i] += __shfl_xor(accT[i], 32, 64);
    }

    // ---- adj @ X2b: half-wave scheme ----
    v8f acc = (v8f)0.f;
    {
        const v8u* __restrict__ Xv = X2v;
        SPMM8_BODY(rpA, evA)
    }
    #pragma unroll
    for (int i = 0; i < 8; ++i) acc[i] += __shfl_xor(acc[i], 32, 64);

    // ---- combine: owner lane l5 (half==0) takes modal slot l5 from group f(l5) ----
    // l5<8: img@l5 | 8..15: txt@(l5-8) | 16..23: img@(l5-8) | 24..31: txt@(l5-16)
    const bool isImg = (l5 < 8) || (l5 >= 16 && l5 < 24);
    const int src = (l5 < 8) ? l5 : (l5 < 16 ? l5 - 8 : (l5 < 24 ? l5 - 8 : l5 - 16));
    v8f mod;
    #pragma unroll
    for (int i = 0; i < 8; ++i) {
        float a = __shfl(accI[i], src, 64);
        float b = __shfl(accT[i], src, 64);
        mod[i] = isImg ? a : b;
    }
    if (half != 0) return;
    const size_t oidx = (size_t)w * DTOT + l5 * 8;
    v8f o = bf8f(*(const v8u*)&E1b[oidx]);
    #pragma unroll
    for (int i = 0; i < 8; ++i) o[i] += acc[i] + mod[i];
    *(v8u*)&OUTb[oidx] = f8bf(o);
}

extern "C" void kernel_launch(void* const* d_in, const int* in_sizes, int n_in,
                              void* d_out, int out_size, void* d_ws, size_t ws_size,
                              hipStream_t stream)
{
    const float* img = (const float*)d_in[0];
    const float* txt = (const float*)d_in[1];
    const int*   ar  = (const int*)d_in[2];
    const int*   ac  = (const int*)d_in[3];
    const float* av  = (const float*)d_in[4];
    const int*   mir = (const int*)d_in[5];
    const int*   mic = (const int*)d_in[6];
    const float* miv = (const float*)d_in[7];
    const int*   mtr = (const int*)d_in[8];
    const int*   mtc = (const int*)d_in[9];
    const float* mtv = (const float*)d_in[10];
    const float* u_sh   = (const float*)d_in[11];
    const float* i_sh   = (const float*)d_in[12];
    const float* Wi_sh  = (const float*)d_in[13];
    const float* bi_sh  = (const float*)d_in[14];
    const float* Wt_sh  = (const float*)d_in[15];
    const float* bt_sh  = (const float*)d_in[16];
    const float* u_vsp  = (const float*)d_in[17];
    const float* i_vsp  = (const float*)d_in[18];
    const float* Wi_vsp = (const float*)d_in[19];
    const float* bi_vsp = (const float*)d_in[20];
    const float* u_tsp  = (const float*)d_in[21];
    const float* i_tsp  = (const float*)d_in[22];
    const float* Wt_tsp = (const float*)d_in[23];
    const float* bt_tsp = (const float*)d_in[24];

    // -------- workspace layout --------
    const size_t NE = (size_t)NN * DTOT;
    unsigned short* X1b  = (unsigned short*)d_ws;        // 35.84 MB
    unsigned short* X2b  = X1b + NE;                     // 35.84 MB
    unsigned short* OUTb = X2b + NE;                     // 35.84 MB
    unsigned short* E1b  = OUTb + NE;                    // 35.84 MB
    unsigned short* C1b  = X1b;                          // alias: X1b dead after comb_all
    float* P = (float*)(E1b + NE);                       // [2][ITEM,256] f32 = 40.96 MB
    unsigned short* WtbI = (unsigned short*)(P + 2 * (size_t)ITEMN * DTOT);  // 1 MB
    unsigned short* WtbT = WtbI + 128 * 4096;
    uint2* evA  = (uint2*)(WtbT + 128 * 768);            // 16 MB
    uint2* evI  = evA + E_MAINN;                         // 8 MB
    uint2* evT  = evI + E_MODALN;                        // 8 MB
    uint2* tmpA = evT + E_MODALN;                        // 16 MB
    uint2* tmpI = tmpA + E_MAINN;                        // 8 MB
    uint2* tmpT = tmpI + E_MODALN;                       // 8 MB
    int*   rpA   = (int*)(tmpT + E_MODALN);              // NN+1 each
    int*   rpI   = rpA + (NN + 4);
    int*   rpT   = rpI + (NN + 4);
    int*   bcount = rpT + (NN + 4);                      // 3*B1
    int*   gbase  = bcount + 3 * B1;                     // 3*(B1+1)
    int*   gcnt   = gbase + 3 * (B1 + 1);                // 3*B1
    float* out   = (float*)d_out;

    const int waveBlocks = (NN * 64) / 256;              // 17500

    // -------- CSR build (LDS-chunked two-level counting sort) --------
    hipMemsetAsync(bcount, 0, 3 * B1 * sizeof(int), stream);
    bucket_count<<<dim3(NBLK1, 3), 256, 0, stream>>>(ar, mir, mtr, bcount);
    bucket_base<<<1, 256, 0, stream>>>(bcount, gbase, gcnt);
    radix_a<<<dim3(NBLK1, 3), 256, 0, stream>>>(ar, ac, av, mir, mic, miv, mtr, mtc, mtv,
                                                gbase, gcnt, tmpA, tmpI, tmpT);
    bucket_sort<<<dim3(B1, 3), 256, 0, stream>>>(gbase, tmpA, tmpI, tmpT,
                                                 evA, evI, evT, rpA, rpI, rpT);

    // -------- W transpose to bf16 --------
    wt_build<<<(128 * 4096 + 255) / 256, 256, 0, stream>>>(Wi_sh, Wi_vsp, 4096, WtbI);
    wt_build<<<(128 * 768  + 255) / 256, 256, 0, stream>>>(Wt_sh, Wt_tsp,  768, WtbT);

    // -------- MFMA projections (K-split x2 partials into P) --------
    gemm_mfma<<<dim3((ITEMN + 63) / 64, 2), 256, 0, stream>>>(img, ITEMN, 4096, WtbI, P, 0, 2);
    gemm_mfma<<<dim3((ITEMN + 63) / 64, 2), 256, 0, stream>>>(txt, ITEMN,  768, WtbT, P, 1, 3);

    // -------- X1b = bf16([uE ; l2norm(A@W+b)]); X2b item rows = bf16(iE) --------
    build_feats<<<NN, 256, 0, stream>>>(P, u_sh, u_vsp, u_tsp, i_sh, i_vsp, i_tsp,
                                        bi_sh, bt_sh, bi_vsp, bt_tsp, X1b, X2b);

    // -------- pass1: E1b = bf16(adj @ X1b); X2b user rows = E1b --------
    spmm_e1<<<waveBlocks, 256, 0, stream>>>(rpA, evA, X1b, E1b, X2b);

    // -------- OUTb = bf16(E1b + adj@X2b + LAM*modal) --------
    comb_all<<<waveBlocks, 256, 0, stream>>>(rpA, evA, rpI, evI, rpT, evT,
                                             X1b, X2b, E1b, OUTb);

    // -------- layer1: C1b = bf16(adj @ OUTb) --------
    spmm_l1<<<waveBlocks, 256, 0, stream>>>(rpA, evA, OUTb, C1b);

    // -------- layer2 + final: out = OUTb + C1b + adj@C1b --------
    fused_final<<<waveBlocks, 256, 0, stream>>>(rpA, evA, C1b, OUTb, out);
}

// Round 10
// 1040.717 us; speedup vs baseline: 1.2226x; 1.0064x over previous
//
#include <hip/hip_runtime.h>

#define USERN 50000
#define ITEMN 20000
#define NN    70000
#define DTOT  256        // 4 branches x 64
#define LAMv  0.2f
#define E_MAINN  2000000
#define E_MODALN 1000000
#define B1    64         // coarse buckets
#define RPB1  1094       // rows per bucket: 64*1094 = 70016 >= 70000
#define CAP   96         // LDS entries per bucket in radix_a
#define FLUSH 64         // flush chunk (512 B)
#define NBLK1 128
#define SPAN  5          // ceil(RPB1/256)

typedef float  v4f  __attribute__((ext_vector_type(4)));
typedef float  v8f  __attribute__((ext_vector_type(8)));
typedef short  v8s  __attribute__((ext_vector_type(8)));
typedef unsigned short v8u __attribute__((ext_vector_type(8)));

// ---------- bf16 helpers ----------
__device__ inline unsigned short f2bf(float f) {           // RNE
    unsigned u = __float_as_uint(f);
    u += 0x7FFFu + ((u >> 16) & 1u);
    return (unsigned short)(u >> 16);
}
__device__ inline v8f bf8f(v8u u) {
    v8f f;
    #pragma unroll
    for (int i = 0; i < 8; ++i) f[i] = __uint_as_float((unsigned)u[i] << 16);
    return f;
}
__device__ inline v8u f8bf(v8f f) {
    v8u u;
    #pragma unroll
    for (int i = 0; i < 8; ++i) u[i] = f2bf(f[i]);
    return u;
}
__device__ inline ushort4 f4bf(float4 f) {
    return make_ushort4(f2bf(f.x), f2bf(f.y), f2bf(f.z), f2bf(f.w));
}

__device__ inline int wave_incl_scan64(int x, int lane) {
    #pragma unroll
    for (int off = 1; off < 64; off <<= 1) {
        int t = __shfl_up(x, off, 64);
        if (lane >= off) x += t;
    }
    return x;
}

// ---------------- W transpose+cvt: Wtb[c][k], c<64 from W0 else W1 -------------------------
__global__ __launch_bounds__(256) void wt_build(
    const float* __restrict__ W0, const float* __restrict__ W1, int K,
    unsigned short* __restrict__ Wtb)
{
    int idx = blockIdx.x * 256 + threadIdx.x;
    if (idx >= 128 * K) return;
    int c = idx / K, k = idx - c * K;
    float v = (c < 64) ? W0[(size_t)k * 64 + c] : W1[(size_t)k * 64 + (c - 64)];
    Wtb[idx] = f2bf(v);
}

// ---------------- MFMA GEMM: P[seg][M][256] partials, K-split x2 ---------------------------
#define LDK 40   // padded k-stride in LDS (80B rows -> conflict-free b128)

__global__ __launch_bounds__(256) void gemm_mfma(
    const float* __restrict__ A, int M, int K,
    const unsigned short* __restrict__ Wtb,
    float* __restrict__ P, int blkA, int blkB)
{
    __shared__ __align__(16) unsigned short As[64 * LDK];
    __shared__ __align__(16) unsigned short Ws[128 * LDK];
    const int tid  = threadIdx.x;
    const int row0 = blockIdx.x * 64;
    const int segLen = K >> 1;
    const int k0   = blockIdx.y * segLen;
    const int kend = k0 + segLen;
    float* outP = P + (size_t)blockIdx.y * ITEMN * DTOT;

    const int w   = tid >> 6;
    const int l   = tid & 63;
    const int l16 = l & 15, kg = l >> 4;

    const int sar = tid >> 2, sak = (tid & 3) * 8;
    const int swc = tid >> 1, swk = (tid & 1) * 16;

    v4f acc[8];
    #pragma unroll
    for (int n = 0; n < 8; ++n) acc[n] = (v4f)0.f;

    for (int kt = k0; kt < kend; kt += 32) {
        __syncthreads();
        {
            int arow = row0 + sar; if (arow >= M) arow = M - 1;
            const float* ap = A + (size_t)arow * K + kt + sak;
            float4 a0 = ((const float4*)ap)[0];
            float4 a1 = ((const float4*)ap)[1];
            *(ushort4*)&As[sar * LDK + sak]     = f4bf(a0);
            *(ushort4*)&As[sar * LDK + sak + 4] = f4bf(a1);
            const unsigned short* wp = Wtb + (size_t)swc * K + kt + swk;
            *(uint4*)&Ws[swc * LDK + swk]     = ((const uint4*)wp)[0];
            *(uint4*)&Ws[swc * LDK + swk + 8] = ((const uint4*)wp)[1];
        }
        __syncthreads();

        v8s af = *(const v8s*)&As[(w * 16 + l16) * LDK + kg * 8];
        #pragma unroll
        for (int n = 0; n < 8; ++n) {
            v8s bf = *(const v8s*)&Ws[(n * 16 + l16) * LDK + kg * 8];
            acc[n] = __builtin_amdgcn_mfma_f32_16x16x32_bf16(af, bf, acc[n], 0, 0, 0);
        }
    }

    #pragma unroll
    for (int n = 0; n < 8; ++n) {
        const int col  = n * 16 + l16;
        const int gcol = (col < 64) ? blkA * 64 + col : blkB * 64 + (col - 64);
        #pragma unroll
        for (int r = 0; r < 4; ++r) {
            int row = row0 + w * 16 + kg * 4 + r;
            if (row < M) outP[(size_t)row * DTOT + gcol] = acc[n][r];
        }
    }
}

// ------- build feats: X1b user=uE, item=l2norm(P-reduce+bias); X2b item=iE ----------------
__global__ __launch_bounds__(256) void build_feats(
    const float* __restrict__ P,
    const float* __restrict__ u_sh, const float* __restrict__ u_vsp, const float* __restrict__ u_tsp,
    const float* __restrict__ i_sh, const float* __restrict__ i_vsp, const float* __restrict__ i_tsp,
    const float* __restrict__ bi_sh, const float* __restrict__ bt_sh,
    const float* __restrict__ bi_vsp, const float* __restrict__ bt_tsp,
    unsigned short* __restrict__ X1b, unsigned short* __restrict__ X2b)
{
    const int n = blockIdx.x;
    const int t = threadIdx.x;
    const int b = t >> 6, k = t & 63;
    if (n < USERN) {
        const float* u = (b < 2) ? u_sh : (b == 2 ? u_vsp : u_tsp);
        X1b[(size_t)n * DTOT + t] = f2bf(u[(size_t)n * 64 + k]);
    } else {
        const int it = n - USERN;
        const size_t SEG = (size_t)ITEMN * DTOT;
        size_t idx = (size_t)it * DTOT + t;
        float f = P[idx] + P[idx + SEG];
        const float* bias = (b == 0) ? bi_sh : (b == 1 ? bt_sh : (b == 2 ? bi_vsp : bt_tsp));
        f += bias[k];
        float s = f * f;
        #pragma unroll
        for (int off = 32; off > 0; off >>= 1) s += __shfl_xor(s, off, 64);
        X1b[(size_t)n * DTOT + t] = f2bf(f / fmaxf(sqrtf(s), 1e-12f));
        const float* p = (b < 2) ? i_sh : (b == 2 ? i_vsp : i_tsp);
        X2b[(size_t)n * DTOT + t] = f2bf(p[(size_t)it * 64 + k]);
    }
}

// ---------------- CSR build: coarse count, bases, LDS-chunked radix, per-bucket sort -------
__global__ __launch_bounds__(256) void bucket_count(
    const int* __restrict__ ar, const int* __restrict__ mir, const int* __restrict__ mtr,
    int* __restrict__ bcount)
{
    const int g = blockIdx.y;
    const int* rows = (g == 0) ? ar : (g == 1 ? mir : mtr);
    const int E = (g == 0) ? E_MAINN : E_MODALN;
    __shared__ int h[B1];
    if (threadIdx.x < B1) h[threadIdx.x] = 0;
    __syncthreads();
    const int chunk = (E + gridDim.x - 1) / gridDim.x;
    const int c0 = blockIdx.x * chunk, c1 = min(c0 + chunk, E);
    for (int i = c0 + threadIdx.x; i < c1; i += 256)
        atomicAdd(&h[rows[i] / RPB1], 1);
    __syncthreads();
    if (threadIdx.x < B1 && h[threadIdx.x])
        atomicAdd(&bcount[g * B1 + threadIdx.x], h[threadIdx.x]);
}

__global__ __launch_bounds__(256) void bucket_base(
    const int* __restrict__ bcount, int* __restrict__ gbase, int* __restrict__ gcnt)
{
    const int g = threadIdx.x >> 6, lane = threadIdx.x & 63;
    if (g < 3) {
        int v = bcount[g * B1 + lane];
        int x = wave_incl_scan64(v, lane);
        gbase[g * (B1 + 1) + lane] = x - v;
        if (lane == 63) gbase[g * (B1 + 1) + B1] = x;
        gcnt[g * B1 + lane] = 0;
    }
}

// Pass A: stage edges per coarse bucket in LDS, flush full 512B chunks (merged writes).
// entry: x = rl(11b)<<17 | col(17b), y = f32 val bits.
__global__ __launch_bounds__(256) void radix_a(
    const int* __restrict__ ar,  const int* __restrict__ ac,  const float* __restrict__ av,
    const int* __restrict__ mir, const int* __restrict__ mic, const float* __restrict__ miv,
    const int* __restrict__ mtr, const int* __restrict__ mtc, const float* __restrict__ mtv,
    const int* __restrict__ gbase, int* __restrict__ gcnt,
    uint2* __restrict__ tmpA, uint2* __restrict__ tmpI, uint2* __restrict__ tmpT)
{
    const int g = blockIdx.y;
    const int* rows   = (g == 0) ? ar : (g == 1 ? mir : mtr);
    const int* cols   = (g == 0) ? ac : (g == 1 ? mic : mtc);
    const float* vals = (g == 0) ? av : (g == 1 ? miv : mtv);
    uint2* tmp        = (g == 0) ? tmpA : (g == 1 ? tmpI : tmpT);
    const int E = (g == 0) ? E_MAINN : E_MODALN;
    const int* gb = gbase + g * (B1 + 1);
    int* gc = gcnt + g * B1;

    __shared__ uint2 buf[B1][CAP];
    __shared__ int bcnt_s[B1];
    const int tid = threadIdx.x;
    if (tid < B1) bcnt_s[tid] = 0;
    __syncthreads();

    const int chunk = (E + gridDim.x - 1) / gridDim.x;
    const int c0 = blockIdx.x * chunk, c1 = min(c0 + chunk, E);
    const int b = tid >> 2, sub = tid & 3;
    const int blane = (tid & 63) & ~3;

    for (int base = c0; base < c1; base += 256) {
        int i = base + tid;
        if (i < c1) {
            int r = rows[i];
            int b1 = r / RPB1;
            int rl = r - b1 * RPB1;
            uint2 entry = make_uint2(((unsigned)rl << 17) | (unsigned)cols[i],
                                     __float_as_uint(vals[i]));
            int slot = atomicAdd(&bcnt_s[b1], 1);
            if (slot < CAP) buf[b1][slot] = entry;
            else tmp[gb[b1] + atomicAdd(&gc[b1], 1)] = entry;   // overflow (≈never)
        }
        __syncthreads();
        int bc = min(bcnt_s[b], CAP);
        if (bc >= FLUSH) {
            int goff = 0;
            if (sub == 0) goff = gb[b] + atomicAdd(&gc[b], FLUSH);
            goff = __shfl(goff, blane, 64);
            for (int t = sub; t < FLUSH; t += 4)
                tmp[goff + t] = buf[b][t];
            int rem = bc - FLUSH;
            for (int t = sub; t < rem; t += 4)
                buf[b][t] = buf[b][FLUSH + t];
            if (sub == 0) bcnt_s[b] = rem;
        }
        __syncthreads();
    }
    // drain remainders
    int bc = min(bcnt_s[b], CAP);
    if (bc > 0) {
        int goff = 0;
        if (sub == 0) goff = gb[b] + atomicAdd(&gc[b], bc);
        goff = __shfl(goff, blane, 64);
        for (int t = sub; t < bc; t += 4)
            tmp[goff + t] = buf[b][t];
    }
}

// Pass B: per coarse bucket: LDS row-histogram -> scan -> write rp -> scatter to final ev.
__global__ __launch_bounds__(256) void bucket_sort(
    const int* __restrict__ gbase,
    const uint2* __restrict__ tmpA, const uint2* __restrict__ tmpI, const uint2* __restrict__ tmpT,
    uint2* __restrict__ evA, uint2* __restrict__ evI, uint2* __restrict__ evT,
    int* __restrict__ rpA, int* __restrict__ rpI, int* __restrict__ rpT)
{
    const int gidx = blockIdx.y;
    const uint2* tmp = (gidx == 0) ? tmpA : (gidx == 1 ? tmpI : tmpT);
    uint2* ev        = (gidx == 0) ? evA  : (gidx == 1 ? evI  : evT);
    int* rp          = (gidx == 0) ? rpA  : (gidx == 1 ? rpI  : rpT);
    const int b1 = blockIdx.x;
    const int r0 = b1 * RPB1;
    const int r1 = min(r0 + RPB1, NN);
    const int nr = r1 - r0;
    const int gb = gbase[gidx * (B1 + 1) + b1];
    const int count = gbase[gidx * (B1 + 1) + b1 + 1] - gb;
    __shared__ int lcnt[RPB1];
    __shared__ int lrp[RPB1];
    __shared__ int wsum[4];
    const int tid = threadIdx.x, lane = tid & 63, wv = tid >> 6;
    for (int t = tid; t < nr; t += 256) lcnt[t] = 0;
    __syncthreads();
    for (int t = tid; t < count; t += 256)
        atomicAdd(&lcnt[tmp[gb + t].x >> 17], 1);
    __syncthreads();
    int loc[SPAN]; int s = 0;
    #pragma unroll
    for (int j = 0; j < SPAN; ++j) {
        int idx = tid * SPAN + j;
        int v = (idx < nr) ? lcnt[idx] : 0;
        loc[j] = s; s += v;
    }
    int x = wave_incl_scan64(s, lane);
    if (lane == 63) wsum[wv] = x;
    __syncthreads();
    int woff = 0;
    for (int i = 0; i < wv; ++i) woff += wsum[i];
    int ex = woff + x - s;
    #pragma unroll
    for (int j = 0; j < SPAN; ++j) {
        int idx = tid * SPAN + j;
        if (idx < nr) lrp[idx] = gb + ex + loc[j];
    }
    __syncthreads();
    for (int t = tid; t < nr; t += 256) rp[r0 + t] = lrp[t];
    if (tid == 0 && r1 == NN) rp[NN] = gb + count;
    __syncthreads();
    int t = tid;
    for (; t + 768 < count; t += 1024) {
        uint2 q0 = tmp[gb + t];
        uint2 q1 = tmp[gb + t + 256];
        uint2 q2 = tmp[gb + t + 512];
        uint2 q3 = tmp[gb + t + 768];
        int p0 = atomicAdd(&lrp[q0.x >> 17], 1);
        int p1 = atomicAdd(&lrp[q1.x >> 17], 1);
        int p2 = atomicAdd(&lrp[q2.x >> 17], 1);
        int p3 = atomicAdd(&lrp[q3.x >> 17], 1);
        ev[p0] = make_uint2(q0.x & 0x1FFFFu, q0.y);
        ev[p1] = make_uint2(q1.x & 0x1FFFFu, q1.y);
        ev[p2] = make_uint2(q2.x & 0x1FFFFu, q2.y);
        ev[p3] = make_uint2(q3.x & 0x1FFFFu, q3.y);
    }
    for (; t < count; t += 256) {
        uint2 q = tmp[gb + t];
        int p = atomicAdd(&lrp[q.x >> 17], 1);
        ev[p] = make_uint2(q.x & 0x1FFFFu, q.y);
    }
}

// -------- CSR SpMM: wave/row, half-wave per edge, 16B lanes, 8 edges in flight -------------
// GATHER(q) must yield a const v8u* base table for column q.x
#define SPMM8_BODY_SEL(RP, EV, SELA, SELB)                                          \
    {                                                                               \
        int e = RP[w]; const int end = RP[w + 1];                                   \
        for (; e + 8 <= end; e += 8) {                                              \
            uint2 q0 = EV[e + half],     q1 = EV[e + 2 + half];                     \
            uint2 q2 = EV[e + 4 + half], q3 = EV[e + 6 + half];                     \
            v8f g0 = bf8f((((int)q0.x < USERN) ? SELA : SELB)[(size_t)q0.x * 32 + l5]); \
            v8f g1 = bf8f((((int)q1.x < USERN) ? SELA : SELB)[(size_t)q1.x * 32 + l5]); \
            v8f g2 = bf8f((((int)q2.x < USERN) ? SELA : SELB)[(size_t)q2.x * 32 + l5]); \
            v8f g3 = bf8f((((int)q3.x < USERN) ? SELA : SELB)[(size_t)q3.x * 32 + l5]); \
            float v0 = __uint_as_float(q0.y), v1 = __uint_as_float(q1.y);           \
            float v2 = __uint_as_float(q2.y), v3 = __uint_as_float(q3.y);           \
            _Pragma("unroll")                                                       \
            for (int i = 0; i < 8; ++i) {                                           \
                acc[i] = fmaf(v0, g0[i], acc[i]); acc[i] = fmaf(v1, g1[i], acc[i]); \
                acc[i] = fmaf(v2, g2[i], acc[i]); acc[i] = fmaf(v3, g3[i], acc[i]); \
            }                                                                       \
        }                                                                           \
        for (; e + 2 <= end; e += 2) {                                              \
            uint2 q = EV[e + half];                                                 \
            v8f g = bf8f((((int)q.x < USERN) ? SELA : SELB)[(size_t)q.x * 32 + l5]);\
            float v = __uint_as_float(q.y);                                         \
            _Pragma("unroll")                                                       \
            for (int i = 0; i < 8; ++i) acc[i] = fmaf(v, g[i], acc[i]);             \
        }                                                                           \
        if (e < end && half == 0) {                                                 \
            uint2 q = EV[e];                                                        \
            v8f g = bf8f((((int)q.x < USERN) ? SELA : SELB)[(size_t)q.x * 32 + l5]);\
            float v = __uint_as_float(q.y);                                         \
            _Pragma("unroll")                                                       \
            for (int i = 0; i < 8; ++i) acc[i] = fmaf(v, g[i], acc[i]);             \
        }                                                                           \
    }

#define SPMM8_BODY(RP, EV, XT) SPMM8_BODY_SEL(RP, EV, XT, XT)

#define SPMM8_PRE                                                                   \
    const int w = (blockIdx.x * blockDim.x + threadIdx.x) >> 6;                     \
    if (w >= NN) return;                                                            \
    const int lane = threadIdx.x & 63;                                              \
    const int half = lane >> 5, l5 = lane & 31;                                     \
    v8f acc = (v8f)0.f;

#define SPMM8_POST                                                                  \
    _Pragma("unroll")                                                               \
    for (int i = 0; i < 8; ++i) acc[i] += __shfl_xor(acc[i], 32, 64);               \
    if (half != 0) return;                                                          \
    const size_t oidx = (size_t)w * DTOT + l5 * 8;

// E1b = bf16(adj @ X1b)
__global__ __launch_bounds__(256) void spmm_e1(
    const int* __restrict__ rp, const uint2* __restrict__ ev,
    const unsigned short* __restrict__ Xb, unsigned short* __restrict__ E1b)
{
    const v8u* __restrict__ Xv = (const v8u*)Xb;
    SPMM8_PRE
    SPMM8_BODY(rp, ev, Xv)
    SPMM8_POST
    *(v8u*)&E1b[oidx] = f8bf(acc);
}

// C1b = bf16(adj @ OUTb)
__global__ __launch_bounds__(256) void spmm_l1(
    const int* __restrict__ rp, const uint2* __restrict__ ev,
    const unsigned short* __restrict__ Xb, unsigned short* __restrict__ C1b)
{
    const v8u* __restrict__ Xv = (const v8u*)Xb;
    SPMM8_PRE
    SPMM8_BODY(rp, ev, Xv)
    SPMM8_POST
    *(v8u*)&C1b[oidx] = f8bf(acc);
}

// out = OUTb + C1b + adj @ C1b   (f32, single final write of d_out)
__global__ __launch_bounds__(256) void fused_final(
    const int* __restrict__ rp, const uint2* __restrict__ ev,
    const unsigned short* __restrict__ Xb, const unsigned short* __restrict__ OUTb,
    float* __restrict__ out)
{
    const v8u* __restrict__ Xv = (const v8u*)Xb;
    SPMM8_PRE
    SPMM8_BODY(rp, ev, Xv)
    SPMM8_POST
    v8f t = bf8f(*(const v8u*)&OUTb[oidx]);
    v8f c = bf8f(Xv[(size_t)w * 32 + l5]);
    #pragma unroll
    for (int i = 0; i < 8; ++i) t[i] += c[i] + acc[i];
    *(v8f*)&out[oidx] = t;
}

// -------- comb_all: OUTb = bf16(E1b + adj@X2 + LAM*(img modal) + LAM*(txt modal)) ----------
// X2 rows: users from E1b, items from X2b. wave per row; modal quarter-wave, 2 edges in flight.
__global__ __launch_bounds__(256) void comb_all(
    const int* __restrict__ rpA, const uint2* __restrict__ evA,
    const int* __restrict__ rpI, const uint2* __restrict__ evI,
    const int* __restrict__ rpT, const uint2* __restrict__ evT,
    const unsigned short* __restrict__ X1b, const unsigned short* __restrict__ X2b,
    const unsigned short* __restrict__ E1b, unsigned short* __restrict__ OUTb)
{
    const int w = (blockIdx.x * blockDim.x + threadIdx.x) >> 6;
    if (w >= NN) return;
    const int lane = threadIdx.x & 63;
    const int half = lane >> 5, l5 = lane & 31;
    const int qt = lane >> 4, l4 = lane & 15;
    const v8u* __restrict__ X1v = (const v8u*)X1b;
    const v8u* __restrict__ X2v = (const v8u*)X2b;
    const v8u* __restrict__ E1v = (const v8u*)E1b;

    // ---- modal loops: 2 edges in flight per quarter-wave ----
    v8f accI = (v8f)0.f, accT = (v8f)0.f;
    {
        const int slot = (l4 >> 3) * 16 + (l4 & 7);
        int e = rpI[w]; const int end = rpI[w + 1];
        for (; e + 8 <= end; e += 8) {
            uint2 qa = evI[e + qt], qb = evI[e + 4 + qt];
            v8f ga = bf8f((((int)qa.x < USERN) ? X1v : X2v)[(size_t)qa.x * 32 + slot]);
            v8f gb = bf8f((((int)qb.x < USERN) ? X1v : X2v)[(size_t)qb.x * 32 + slot]);
            float va = __uint_as_float(qa.y) * LAMv;
            float vb = __uint_as_float(qb.y) * LAMv;
            #pragma unroll
            for (int i = 0; i < 8; ++i) {
                accI[i] = fmaf(va, ga[i], accI[i]);
                accI[i] = fmaf(vb, gb[i], accI[i]);
            }
        }
        for (; e + 4 <= end; e += 4) {
            uint2 q = evI[e + qt];
            v8f g = bf8f((((int)q.x < USERN) ? X1v : X2v)[(size_t)q.x * 32 + slot]);
            float v = __uint_as_float(q.y) * LAMv;
            #pragma unroll
            for (int i = 0; i < 8; ++i) accI[i] = fmaf(v, g[i], accI[i]);
        }
        if (qt < end - e) {
            uint2 q = evI[e + qt];
            v8f g = bf8f((((int)q.x < USERN) ? X1v : X2v)[(size_t)q.x * 32 + slot]);
            float v = __uint_as_float(q.y) * LAMv;
            #pragma unroll
            for (int i = 0; i < 8; ++i) accI[i] = fmaf(v, g[i], accI[i]);
        }
    }
    {
        const int slot = 8 + (l4 >> 3) * 16 + (l4 & 7);
        int e = rpT[w]; const int end = rpT[w + 1];
        for (; e + 8 <= end; e += 8) {
            uint2 qa = evT[e + qt], qb = evT[e + 4 + qt];
            v8f ga = bf8f((((int)qa.x < USERN) ? X1v : X2v)[(size_t)qa.x * 32 + slot]);
            v8f gb = bf8f((((int)qb.x < USERN) ? X1v : X2v)[(size_t)qb.x * 32 + slot]);
            float va = __uint_as_float(qa.y) * LAMv;
            float vb = __uint_as_float(qb.y) * LAMv;
            #pragma unroll
            for (int i = 0; i < 8; ++i) {
                accT[i] = fmaf(va, ga[i], accT[i]);
                accT[i] = fmaf(vb, gb[i], accT[i]);
            }
        }
        for (; e + 4 <= end; e += 4) {
            uint2 q = evT[e + qt];
            v8f g = bf8f((((int)q.x < USERN) ? X1v : X2v)[(size_t)q.x * 32 + slot]);
            float v = __uint_as_float(q.y) * LAMv;
            #pragma unroll
            for (int i = 0; i < 8; ++i) accT[i] = fmaf(v, g[i], accT[i]);
        }
        if (qt < end - e) {
            uint2 q = evT[e + qt];
            v8f g = bf8f((((int)q.x < USERN) ? X1v : X2v)[(size_t)q.x * 32 + slot]);
            float v = __uint_as_float(q.y) * LAMv;
            #pragma unroll
            for (int i = 0; i < 8; ++i) accT[i] = fmaf(v, g[i], accT[i]);
        }
    }
    #pragma unroll
    for (int i = 0; i < 8; ++i) {
        accI[i] += __shfl_xor(accI[i], 16, 64);
        accI[i] += __shfl_xor(accI[i], 32, 64);
        accT[i] += __shfl_xor(accT[i], 16, 64);
        accT[i] += __shfl_xor(accT[i], 32, 64);
    }

    // ---- adj @ X2 (users from E1b, items from X2b): half-wave scheme ----
    v8f acc = (v8f)0.f;
    SPMM8_BODY_SEL(rpA, evA, E1v, X2v)
    #pragma unroll
    for (int i = 0; i < 8; ++i) acc[i] += __shfl_xor(acc[i], 32, 64);

    // ---- combine: owner lane l5 (half==0) takes modal slot l5 from group f(l5) ----
    const bool isImg = (l5 < 8) || (l5 >= 16 && l5 < 24);
    const int src = (l5 < 8) ? l5 : (l5 < 16 ? l5 - 8 : (l5 < 24 ? l5 - 8 : l5 - 16));
    v8f mod;
    #pragma unroll
    for (int i = 0; i < 8; ++i) {
        float a = __shfl(accI[i], src, 64);
        float b = __shfl(accT[i], src, 64);
        mod[i] = isImg ? a : b;
    }
    if (half != 0) return;
    const size_t oidx = (size_t)w * DTOT + l5 * 8;
    v8f o = bf8f(*(const v8u*)&E1b[oidx]);
    #pragma unroll
    for (int i = 0; i < 8; ++i) o[i] += acc[i] + mod[i];
    *(v8u*)&OUTb[oidx] = f8bf(o);
}

extern "C" void kernel_launch(void* const* d_in, const int* in_sizes, int n_in,
                              void* d_out, int out_size, void* d_ws, size_t ws_size,
                              hipStream_t stream)
{
    const float* img = (const float*)d_in[0];
    const float* txt = (const float*)d_in[1];
    const int*   ar  = (const int*)d_in[2];
    const int*   ac  = (const int*)d_in[3];
    const float* av  = (const float*)d_in[4];
    const int*   mir = (const int*)d_in[5];
    const int*   mic = (const int*)d_in[6];
    const float* miv = (const float*)d_in[7];
    const int*   mtr = (const int*)d_in[8];
    const int*   mtc = (const int*)d_in[9];
    const float* mtv = (const float*)d_in[10];
    const float* u_sh   = (const float*)d_in[11];
    const float* i_sh   = (const float*)d_in[12];
    const float* Wi_sh  = (const float*)d_in[13];
    const float* bi_sh  = (const float*)d_in[14];
    const float* Wt_sh  = (const float*)d_in[15];
    const float* bt_sh  = (const float*)d_in[16];
    const float* u_vsp  = (const float*)d_in[17];
    const float* i_vsp  = (const float*)d_in[18];
    const float* Wi_vsp = (const float*)d_in[19];
    const float* bi_vsp = (const float*)d_in[20];
    const float* u_tsp  = (const float*)d_in[21];
    const float* i_tsp  = (const float*)d_in[22];
    const float* Wt_tsp = (const float*)d_in[23];
    const float* bt_tsp = (const float*)d_in[24];

    // -------- workspace layout --------
    const size_t NE = (size_t)NN * DTOT;
    unsigned short* X1b  = (unsigned short*)d_ws;        // 35.84 MB
    unsigned short* X2b  = X1b + NE;                     // 35.84 MB (item rows only used)
    unsigned short* OUTb = X2b + NE;                     // 35.84 MB
    unsigned short* E1b  = OUTb + NE;                    // 35.84 MB
    unsigned short* C1b  = X1b;                          // alias: X1b dead after comb_all
    float* P = (float*)(E1b + NE);                       // [2][ITEM,256] f32 = 40.96 MB
    unsigned short* WtbI = (unsigned short*)(P + 2 * (size_t)ITEMN * DTOT);  // 1 MB
    unsigned short* WtbT = WtbI + 128 * 4096;
    uint2* evA  = (uint2*)(WtbT + 128 * 768);            // 16 MB
    uint2* evI  = evA + E_MAINN;                         // 8 MB
    uint2* evT  = evI + E_MODALN;                        // 8 MB
    uint2* tmpA = evT + E_MODALN;                        // 16 MB
    uint2* tmpI = tmpA + E_MAINN;                        // 8 MB
    uint2* tmpT = tmpI + E_MODALN;                       // 8 MB
    int*   rpA   = (int*)(tmpT + E_MODALN);              // NN+1 each
    int*   rpI   = rpA + (NN + 4);
    int*   rpT   = rpI + (NN + 4);
    int*   bcount = rpT + (NN + 4);                      // 3*B1
    int*   gbase  = bcount + 3 * B1;                     // 3*(B1+1)
    int*   gcnt   = gbase + 3 * (B1 + 1);                // 3*B1
    float* out   = (float*)d_out;

    const int waveBlocks = (NN * 64) / 256;              // 17500

    // -------- CSR build (LDS-chunked two-level counting sort) --------
    hipMemsetAsync(bcount, 0, 3 * B1 * sizeof(int), stream);
    bucket_count<<<dim3(NBLK1, 3), 256, 0, stream>>>(ar, mir, mtr, bcount);
    bucket_base<<<1, 256, 0, stream>>>(bcount, gbase, gcnt);
    radix_a<<<dim3(NBLK1, 3), 256, 0, stream>>>(ar, ac, av, mir, mic, miv, mtr, mtc, mtv,
                                                gbase, gcnt, tmpA, tmpI, tmpT);
    bucket_sort<<<dim3(B1, 3), 256, 0, stream>>>(gbase, tmpA, tmpI, tmpT,
                                                 evA, evI, evT, rpA, rpI, rpT);

    // -------- W transpose to bf16 --------
    wt_build<<<(128 * 4096 + 255) / 256, 256, 0, stream>>>(Wi_sh, Wi_vsp, 4096, WtbI);
    wt_build<<<(128 * 768  + 255) / 256, 256, 0, stream>>>(Wt_sh, Wt_tsp,  768, WtbT);

    // -------- MFMA projections (K-split x2 partials into P) --------
    gemm_mfma<<<dim3((ITEMN + 63) / 64, 2), 256, 0, stream>>>(img, ITEMN, 4096, WtbI, P, 0, 2);
    gemm_mfma<<<dim3((ITEMN + 63) / 64, 2), 256, 0, stream>>>(txt, ITEMN,  768, WtbT, P, 1, 3);

    // -------- X1b = bf16([uE ; l2norm(A@W+b)]); X2b item rows = bf16(iE) --------
    build_feats<<<NN, 256, 0, stream>>>(P, u_sh, u_vsp, u_tsp, i_sh, i_vsp, i_tsp,
                                        bi_sh, bt_sh, bi_vsp, bt_tsp, X1b, X2b);

    // -------- pass1: E1b = bf16(adj @ X1b) --------
    spmm_e1<<<waveBlocks, 256, 0, stream>>>(rpA, evA, X1b, E1b);

    // -------- OUTb = bf16(E1b + adj@[E1b_users;iE] + LAM*modal) --------
    comb_all<<<waveBlocks, 256, 0, stream>>>(rpA, evA, rpI, evI, rpT, evT,
                                             X1b, X2b, E1b, OUTb);

    // -------- layer1: C1b = bf16(adj @ OUTb) --------
    spmm_l1<<<waveBlocks, 256, 0, stream>>>(rpA, evA, OUTb, C1b);

    // -------- layer2 + final: out = OUTb + C1b + adj@C1b --------
    fused_final<<<waveBlocks, 256, 0, stream>>>(rpA, evA, C1b, OUTb, out);
}